// Round 1
// baseline (833.895 us; speedup 1.0000x reference)
//
#include <hip/hip_runtime.h>

#define NN 50000
#define NE 1600000
#define ETOT (NE + NN)
#define NG 512
#define NEG 0.2f

// ---------------- workspace layout (floats) ----------------
// h1     : [NN*64]           off 0
// aS1    : [NN*8]            off NN*64
// aD1    : [NN*8]            off NN*72
// denom1 : [NN*8]            off NN*80   <- zero from here
// out1   : [NN*64]           off NN*88
// denom2 : [NN*1]            off NN*152
// out2   : [NN*2]            off NN*153  <- zero span = 75*NN floats
// h2     : [NN*2]            off NN*155
// aS2    : [NN*1]            off NN*157
// aD2    : [NN*1]            off NN*158
// total  : NN*159 floats ~ 31.8 MB

__global__ __launch_bounds__(256) void k_zero(float* __restrict__ wsz,
                                              float* __restrict__ out, int nz) {
    int i = blockIdx.x * 256 + threadIdx.x;
    if (i < nz) wsz[i] = 0.f;
    else if (i < nz + NG * 2) out[i - nz] = 0.f;
}

// per-node: h1 = x @ W1, plus per-head attention coefficients
__global__ __launch_bounds__(256) void k_linear1(const float* __restrict__ x,
                                                 const float* __restrict__ W1,
                                                 const float* __restrict__ attS,
                                                 const float* __restrict__ attD,
                                                 float* __restrict__ h1,
                                                 float* __restrict__ aS,
                                                 float* __restrict__ aD) {
    __shared__ float xs[4][136];
    const int sub = threadIdx.x >> 6;
    const int j   = threadIdx.x & 63;
    const int n   = blockIdx.x * 4 + sub;   // NN % 4 == 0, no guard needed

    for (int k = j; k < 133; k += 64) xs[sub][k] = x[n * 133 + k];
    __syncthreads();

    float acc = 0.f;
#pragma unroll 7
    for (int k = 0; k < 133; ++k) acc += xs[sub][k] * W1[k * 64 + j];

    h1[n * 64 + j] = acc;

    const int head = j >> 3, c = j & 7;
    float ps = acc * attS[head * 8 + c];
    float pd = acc * attD[head * 8 + c];
#pragma unroll
    for (int o = 1; o < 8; o <<= 1) {
        ps += __shfl_xor(ps, o, 64);
        pd += __shfl_xor(pd, o, 64);
    }
    if (c == 0) {
        aS[n * 8 + head] = ps;
        aD[n * 8 + head] = pd;
    }
}

// one thread per (edge, head): accumulate softmax denominator
__global__ __launch_bounds__(256) void k_edge_denom1(const int* __restrict__ ei,
                                                     const float* __restrict__ aS,
                                                     const float* __restrict__ aD,
                                                     float* __restrict__ denom) {
    long long gid = (long long)blockIdx.x * 256 + threadIdx.x;
    int e = (int)(gid >> 3);
    int h = (int)(gid & 7);
    if (e >= ETOT) return;
    int s, d;
    if (e < NE) { s = ei[e]; d = ei[NE + e]; }
    else        { s = d = e - NE; }
    float ev = aS[s * 8 + h] + aD[d * 8 + h];
    ev = ev > 0.f ? ev : NEG * ev;
    atomicAdd(&denom[d * 8 + h], expf(ev));
}

// one thread per (edge, out-col): weighted scatter into out1
__global__ __launch_bounds__(256) void k_edge_msg1(const int* __restrict__ ei,
                                                   const float* __restrict__ aS,
                                                   const float* __restrict__ aD,
                                                   const float* __restrict__ denom,
                                                   const float* __restrict__ h1,
                                                   float* __restrict__ out1) {
    long long gid = (long long)blockIdx.x * 256 + threadIdx.x;
    int e = (int)(gid >> 6);
    int j = (int)(gid & 63);
    if (e >= ETOT) return;
    int s, d;
    if (e < NE) { s = ei[e]; d = ei[NE + e]; }
    else        { s = d = e - NE; }
    const int h = j >> 3;
    float ev = aS[s * 8 + h] + aD[d * 8 + h];
    ev = ev > 0.f ? ev : NEG * ev;
    float alpha = expf(ev) / denom[d * 8 + h];
    atomicAdd(&out1[d * 64 + j], h1[s * 64 + j] * alpha);
}

// per-node: hE = elu(out1 + b1); h2 = hE @ W2 (64 -> 2); attention coefs
__global__ __launch_bounds__(256) void k_linear2(const float* __restrict__ out1,
                                                 const float* __restrict__ b1,
                                                 const float* __restrict__ W2,
                                                 const float* __restrict__ attS2,
                                                 const float* __restrict__ attD2,
                                                 float* __restrict__ h2,
                                                 float* __restrict__ aS2,
                                                 float* __restrict__ aD2) {
    const int sub = threadIdx.x >> 6;
    const int j   = threadIdx.x & 63;
    const int n   = blockIdx.x * 4 + sub;

    float v = out1[n * 64 + j] + b1[j];
    v = v > 0.f ? v : (expf(v) - 1.f);
    float p0 = v * W2[j * 2 + 0];
    float p1 = v * W2[j * 2 + 1];
#pragma unroll
    for (int o = 1; o < 64; o <<= 1) {
        p0 += __shfl_xor(p0, o, 64);
        p1 += __shfl_xor(p1, o, 64);
    }
    if (j == 0) {
        h2[n * 2 + 0] = p0;
        h2[n * 2 + 1] = p1;
        aS2[n] = p0 * attS2[0] + p1 * attS2[1];
        aD2[n] = p0 * attD2[0] + p1 * attD2[1];
    }
}

__global__ __launch_bounds__(256) void k_edge_denom2(const int* __restrict__ ei,
                                                     const float* __restrict__ aS2,
                                                     const float* __restrict__ aD2,
                                                     float* __restrict__ denom2) {
    int e = blockIdx.x * 256 + threadIdx.x;
    if (e >= ETOT) return;
    int s, d;
    if (e < NE) { s = ei[e]; d = ei[NE + e]; }
    else        { s = d = e - NE; }
    float ev = aS2[s] + aD2[d];
    ev = ev > 0.f ? ev : NEG * ev;
    atomicAdd(&denom2[d], expf(ev));
}

__global__ __launch_bounds__(256) void k_edge_msg2(const int* __restrict__ ei,
                                                   const float* __restrict__ aS2,
                                                   const float* __restrict__ aD2,
                                                   const float* __restrict__ denom2,
                                                   const float* __restrict__ h2,
                                                   float* __restrict__ out2) {
    int e = blockIdx.x * 256 + threadIdx.x;
    if (e >= ETOT) return;
    int s, d;
    if (e < NE) { s = ei[e]; d = ei[NE + e]; }
    else        { s = d = e - NE; }
    float ev = aS2[s] + aD2[d];
    ev = ev > 0.f ? ev : NEG * ev;
    float alpha = expf(ev) / denom2[d];
    atomicAdd(&out2[d * 2 + 0], h2[s * 2 + 0] * alpha);
    atomicAdd(&out2[d * 2 + 1], h2[s * 2 + 1] * alpha);
}

__global__ __launch_bounds__(256) void k_pool(const float* __restrict__ out2,
                                              const int* __restrict__ batch,
                                              const float* __restrict__ b2,
                                              float* __restrict__ out) {
    int n = blockIdx.x * 256 + threadIdx.x;
    if (n >= NN) return;
    int g = batch[n];
    atomicAdd(&out[g * 2 + 0], out2[n * 2 + 0] + b2[0]);
    atomicAdd(&out[g * 2 + 1], out2[n * 2 + 1] + b2[1]);
}

extern "C" void kernel_launch(void* const* d_in, const int* in_sizes, int n_in,
                              void* d_out, int out_size, void* d_ws, size_t ws_size,
                              hipStream_t stream) {
    const float* x     = (const float*)d_in[0];
    const int*   ei    = (const int*)d_in[1];
    const int*   batch = (const int*)d_in[2];
    const float* W1    = (const float*)d_in[3];
    const float* attS1 = (const float*)d_in[4];
    const float* attD1 = (const float*)d_in[5];
    const float* b1    = (const float*)d_in[6];
    const float* W2    = (const float*)d_in[7];
    const float* attS2 = (const float*)d_in[8];
    const float* attD2 = (const float*)d_in[9];
    const float* b2    = (const float*)d_in[10];
    float* out = (float*)d_out;

    float* ws     = (float*)d_ws;
    float* h1     = ws;
    float* aS1    = ws + (size_t)NN * 64;
    float* aD1    = ws + (size_t)NN * 72;
    float* denom1 = ws + (size_t)NN * 80;
    float* out1   = ws + (size_t)NN * 88;
    float* denom2 = ws + (size_t)NN * 152;
    float* out2   = ws + (size_t)NN * 153;
    float* h2     = ws + (size_t)NN * 155;
    float* aS2    = ws + (size_t)NN * 157;
    float* aD2    = ws + (size_t)NN * 158;

    const int nz = NN * 75;  // denom1..out2 span
    {
        int total = nz + NG * 2;
        k_zero<<<(total + 255) / 256, 256, 0, stream>>>(denom1, out, nz);
    }
    k_linear1<<<NN / 4, 256, 0, stream>>>(x, W1, attS1, attD1, h1, aS1, aD1);
    {
        long long total = (long long)ETOT * 8;
        k_edge_denom1<<<(int)((total + 255) / 256), 256, 0, stream>>>(ei, aS1, aD1, denom1);
    }
    {
        long long total = (long long)ETOT * 64;
        k_edge_msg1<<<(int)((total + 255) / 256), 256, 0, stream>>>(ei, aS1, aD1, denom1, h1, out1);
    }
    k_linear2<<<NN / 4, 256, 0, stream>>>(out1, b1, W2, attS2, attD2, h2, aS2, aD2);
    k_edge_denom2<<<(ETOT + 255) / 256, 256, 0, stream>>>(ei, aS2, aD2, denom2);
    k_edge_msg2<<<(ETOT + 255) / 256, 256, 0, stream>>>(ei, aS2, aD2, denom2, h2, out2);
    k_pool<<<(NN + 255) / 256, 256, 0, stream>>>(out2, batch, b2, out);
}

// Round 2
// 447.170 us; speedup vs baseline: 1.8648x; 1.8648x over previous
//
#include <hip/hip_runtime.h>

#define NN 50000
#define NE 1600000
#define ETOT (NE + NN)
#define NG 512
#define NEG 0.2f

// ---------------- workspace layout (4-byte units) ----------------
// h1       : [NN*64] f   off 0
// aS1      : [NN*8]  f   off NN*64
// aD1      : [NN*8]  f   off NN*72
// h2       : [NN*2]  f   off NN*80
// aS2      : [NN]    f   off NN*82
// aD2      : [NN]    f   off NN*83
// deg      : [NN]    i   off NN*84   <- zero deg+cursor (2*NN) each call
// cursor   : [NN]    i   off NN*85
// row_start: [NN+1]  i   off NN*86
// bsum     : [256]   i   off NN*87 + 64
// csr      : [ETOT]  i   off NN*88
// total ~ 24.2 MB

__global__ __launch_bounds__(256) void k_zero(int* __restrict__ degcur,
                                              float* __restrict__ out) {
    int i = blockIdx.x * 256 + threadIdx.x;
    if (i < 2 * NN) degcur[i] = 0;
    else if (i < 2 * NN + NG * 2) out[i - 2 * NN] = 0.f;
}

// per-node: h1 = x @ W1, plus per-head attention coefficients
__global__ __launch_bounds__(256) void k_linear1(const float* __restrict__ x,
                                                 const float* __restrict__ W1,
                                                 const float* __restrict__ attS,
                                                 const float* __restrict__ attD,
                                                 float* __restrict__ h1,
                                                 float* __restrict__ aS,
                                                 float* __restrict__ aD) {
    __shared__ float xs[4][136];
    const int sub = threadIdx.x >> 6;
    const int j   = threadIdx.x & 63;
    const int n   = blockIdx.x * 4 + sub;   // NN % 4 == 0

    for (int k = j; k < 133; k += 64) xs[sub][k] = x[n * 133 + k];
    __syncthreads();

    float acc = 0.f;
#pragma unroll 7
    for (int k = 0; k < 133; ++k) acc += xs[sub][k] * W1[k * 64 + j];

    h1[n * 64 + j] = acc;

    const int head = j >> 3, c = j & 7;
    float ps = acc * attS[head * 8 + c];
    float pd = acc * attD[head * 8 + c];
#pragma unroll
    for (int o = 1; o < 8; o <<= 1) {
        ps += __shfl_xor(ps, o, 64);
        pd += __shfl_xor(pd, o, 64);
    }
    if (c == 0) {
        aS[n * 8 + head] = ps;
        aD[n * 8 + head] = pd;
    }
}

// -------- CSR build --------
__global__ __launch_bounds__(256) void k_count(const int* __restrict__ ei,
                                               int* __restrict__ deg) {
    int e = blockIdx.x * 256 + threadIdx.x;
    if (e >= ETOT) return;
    int d = (e < NE) ? ei[NE + e] : e - NE;
    atomicAdd(&deg[d], 1);
}

__global__ __launch_bounds__(256) void k_scan1(const int* __restrict__ deg,
                                               int* __restrict__ bsum) {
    __shared__ int s[256];
    int i = blockIdx.x * 256 + threadIdx.x;
    s[threadIdx.x] = (i < NN) ? deg[i] : 0;
    __syncthreads();
    for (int o = 128; o > 0; o >>= 1) {
        if (threadIdx.x < o) s[threadIdx.x] += s[threadIdx.x + o];
        __syncthreads();
    }
    if (threadIdx.x == 0) bsum[blockIdx.x] = s[0];
}

__global__ __launch_bounds__(256) void k_scan2(int* __restrict__ bsum, int nb) {
    __shared__ int s[256];
    int t = threadIdx.x;
    int v = (t < nb) ? bsum[t] : 0;
    s[t] = v;
    __syncthreads();
    for (int o = 1; o < 256; o <<= 1) {
        int u = (t >= o) ? s[t - o] : 0;
        __syncthreads();
        s[t] += u;
        __syncthreads();
    }
    if (t < nb) bsum[t] = s[t] - v;  // exclusive
}

__global__ __launch_bounds__(256) void k_scan3(const int* __restrict__ deg,
                                               const int* __restrict__ bsum,
                                               int* __restrict__ row_start) {
    __shared__ int s[256];
    int t = threadIdx.x;
    int i = blockIdx.x * 256 + t;
    int v = (i < NN) ? deg[i] : 0;
    s[t] = v;
    __syncthreads();
    for (int o = 1; o < 256; o <<= 1) {
        int u = (t >= o) ? s[t - o] : 0;
        __syncthreads();
        s[t] += u;
        __syncthreads();
    }
    if (i < NN) row_start[i] = bsum[blockIdx.x] + s[t] - v;
    if (i == 0) row_start[NN] = ETOT;
}

__global__ __launch_bounds__(256) void k_scatter(const int* __restrict__ ei,
                                                 const int* __restrict__ row_start,
                                                 int* __restrict__ cursor,
                                                 int* __restrict__ csr) {
    int e = blockIdx.x * 256 + threadIdx.x;
    if (e >= ETOT) return;
    int s, d;
    if (e < NE) { s = ei[e]; d = ei[NE + e]; }
    else        { s = d = e - NE; }
    int pos = atomicAdd(&cursor[d], 1);
    csr[row_start[d] + pos] = s;
}

// -------- layer-1 gather: softmax-aggregate + bias + ELU + linear2 + attn coefs --------
__global__ __launch_bounds__(256) void k_gather1(const int* __restrict__ csr,
                                                 const int* __restrict__ row_start,
                                                 const float* __restrict__ aS,
                                                 const float* __restrict__ aD,
                                                 const float* __restrict__ h1,
                                                 const float* __restrict__ b1,
                                                 const float* __restrict__ W2,
                                                 const float* __restrict__ attS2,
                                                 const float* __restrict__ attD2,
                                                 float* __restrict__ h2,
                                                 float* __restrict__ aS2,
                                                 float* __restrict__ aD2) {
    const int n    = (blockIdx.x * 256 + threadIdx.x) >> 6;  // grid exact
    const int lane = threadIdx.x & 63;
    const int h    = lane >> 3;

    const float aDd = aD[n * 8 + h];
    const int e0 = row_start[n], e1 = row_start[n + 1];

    float acc = 0.f, den = 0.f;
    for (int base = e0; base < e1; base += 64) {
        int cnt = min(64, e1 - base);
        int sv = (base + lane < e1) ? csr[base + lane] : 0;
        for (int i = 0; i < cnt; ++i) {
            int s = __shfl(sv, i, 64);
            float ev = aS[s * 8 + h] + aDd;
            ev = ev > 0.f ? ev : NEG * ev;
            float ex = expf(ev);
            den += ex;
            acc += ex * h1[s * 64 + lane];
        }
    }
    float v = acc / fmaxf(den, 1e-16f) + b1[lane];
    v = v > 0.f ? v : (expf(v) - 1.f);   // ELU

    float p0 = v * W2[lane * 2 + 0];
    float p1 = v * W2[lane * 2 + 1];
#pragma unroll
    for (int o = 1; o < 64; o <<= 1) {
        p0 += __shfl_xor(p0, o, 64);
        p1 += __shfl_xor(p1, o, 64);
    }
    if (lane == 0) {
        h2[n * 2 + 0] = p0;
        h2[n * 2 + 1] = p1;
        aS2[n] = p0 * attS2[0] + p1 * attS2[1];
        aD2[n] = p0 * attD2[0] + p1 * attD2[1];
    }
}

// -------- layer-2 gather + graph pool --------
__global__ __launch_bounds__(256) void k_gather2(const int* __restrict__ csr,
                                                 const int* __restrict__ row_start,
                                                 const float* __restrict__ aS2,
                                                 const float* __restrict__ aD2,
                                                 const float* __restrict__ h2,
                                                 const int* __restrict__ batch,
                                                 const float* __restrict__ b2,
                                                 float* __restrict__ out) {
    const int n    = (blockIdx.x * 256 + threadIdx.x) >> 6;
    const int lane = threadIdx.x & 63;

    const float aDd = aD2[n];
    const int e0 = row_start[n], e1 = row_start[n + 1];

    float den = 0.f, p0 = 0.f, p1 = 0.f;
    for (int e = e0 + lane; e < e1; e += 64) {
        int s = csr[e];
        float ev = aS2[s] + aDd;
        ev = ev > 0.f ? ev : NEG * ev;
        float ex = expf(ev);
        den += ex;
        p0 += ex * h2[s * 2 + 0];
        p1 += ex * h2[s * 2 + 1];
    }
#pragma unroll
    for (int o = 1; o < 64; o <<= 1) {
        den += __shfl_xor(den, o, 64);
        p0  += __shfl_xor(p0, o, 64);
        p1  += __shfl_xor(p1, o, 64);
    }
    if (lane == 0) {
        float inv = 1.f / fmaxf(den, 1e-16f);
        int g = batch[n];
        atomicAdd(&out[g * 2 + 0], p0 * inv + b2[0]);
        atomicAdd(&out[g * 2 + 1], p1 * inv + b2[1]);
    }
}

extern "C" void kernel_launch(void* const* d_in, const int* in_sizes, int n_in,
                              void* d_out, int out_size, void* d_ws, size_t ws_size,
                              hipStream_t stream) {
    const float* x     = (const float*)d_in[0];
    const int*   ei    = (const int*)d_in[1];
    const int*   batch = (const int*)d_in[2];
    const float* W1    = (const float*)d_in[3];
    const float* attS1 = (const float*)d_in[4];
    const float* attD1 = (const float*)d_in[5];
    const float* b1    = (const float*)d_in[6];
    const float* W2    = (const float*)d_in[7];
    const float* attS2 = (const float*)d_in[8];
    const float* attD2 = (const float*)d_in[9];
    const float* b2    = (const float*)d_in[10];
    float* out = (float*)d_out;

    float* ws  = (float*)d_ws;
    float* h1  = ws;
    float* aS1 = ws + (size_t)NN * 64;
    float* aD1 = ws + (size_t)NN * 72;
    float* h2  = ws + (size_t)NN * 80;
    float* aS2 = ws + (size_t)NN * 82;
    float* aD2 = ws + (size_t)NN * 83;
    int*   deg       = (int*)(ws + (size_t)NN * 84);
    int*   cursor    = (int*)(ws + (size_t)NN * 85);
    int*   row_start = (int*)(ws + (size_t)NN * 86);
    int*   bsum      = (int*)(ws + (size_t)NN * 87 + 64);
    int*   csr       = (int*)(ws + (size_t)NN * 88);

    const int NB_SCAN = (NN + 255) / 256;  // 196

    k_zero<<<(2 * NN + NG * 2 + 255) / 256, 256, 0, stream>>>(deg, out);
    k_linear1<<<NN / 4, 256, 0, stream>>>(x, W1, attS1, attD1, h1, aS1, aD1);
    k_count<<<(ETOT + 255) / 256, 256, 0, stream>>>(ei, deg);
    k_scan1<<<NB_SCAN, 256, 0, stream>>>(deg, bsum);
    k_scan2<<<1, 256, 0, stream>>>(bsum, NB_SCAN);
    k_scan3<<<NB_SCAN, 256, 0, stream>>>(deg, bsum, row_start);
    k_scatter<<<(ETOT + 255) / 256, 256, 0, stream>>>(ei, row_start, cursor, csr);
    k_gather1<<<NN / 4, 256, 0, stream>>>(csr, row_start, aS1, aD1, h1, b1, W2,
                                          attS2, attD2, h2, aS2, aD2);
    k_gather2<<<NN / 4, 256, 0, stream>>>(csr, row_start, aS2, aD2, h2, batch, b2, out);
}

// Round 3
// 355.726 us; speedup vs baseline: 2.3442x; 1.2571x over previous
//
#include <hip/hip_runtime.h>
#include <hip/hip_fp16.h>

#define NN 50000
#define NE 1600000
#define NG 512
#define NEG 0.2f

// ---------------- workspace layout (4-byte units) ----------------
// h1h      : [NN*64] half = NN*32 f   off 0
// aS1      : [NN*8]  f                off NN*32
// aD1      : [NN*8]  f                off NN*40
// h2       : [NN*2]  f                off NN*48
// aS2      : [NN]    f                off NN*50
// aD2      : [NN]    f                off NN*51
// deg      : [NN]    i                off NN*52   <- zeroed each call
// row_start: [NN+1]  i                off NN*53
// bsum     : [256]   i                off NN*54 + 64
// pos      : [NE]    i                off NN*55
// csr      : [NE]    i                off NN*55 + NE
// total ~ 24 MB

__global__ __launch_bounds__(256) void k_zero(int* __restrict__ deg,
                                              float* __restrict__ out) {
    int i = blockIdx.x * 256 + threadIdx.x;
    if (i < NN) deg[i] = 0;
    else if (i < NN + NG * 2) out[i - NN] = 0.f;
}

// per-node: h1 = x @ W1 (stored fp16), plus per-head attention coefficients
__global__ __launch_bounds__(256) void k_linear1(const float* __restrict__ x,
                                                 const float* __restrict__ W1,
                                                 const float* __restrict__ attS,
                                                 const float* __restrict__ attD,
                                                 __half* __restrict__ h1h,
                                                 float* __restrict__ aS,
                                                 float* __restrict__ aD) {
    __shared__ float xs[4][136];
    const int sub = threadIdx.x >> 6;
    const int j   = threadIdx.x & 63;
    const int n   = blockIdx.x * 4 + sub;   // NN % 4 == 0

    for (int k = j; k < 133; k += 64) xs[sub][k] = x[n * 133 + k];
    __syncthreads();

    float acc = 0.f;
#pragma unroll 7
    for (int k = 0; k < 133; ++k) acc += xs[sub][k] * W1[k * 64 + j];

    h1h[n * 64 + j] = __float2half(acc);

    const int head = j >> 3, c = j & 7;
    float ps = acc * attS[head * 8 + c];
    float pd = acc * attD[head * 8 + c];
#pragma unroll
    for (int o = 1; o < 8; o <<= 1) {
        ps += __shfl_xor(ps, o, 64);
        pd += __shfl_xor(pd, o, 64);
    }
    if (c == 0) {
        aS[n * 8 + head] = ps;
        aD[n * 8 + head] = pd;
    }
}

// -------- CSR build (real edges only; self-loops handled inline in gathers) --------
__global__ __launch_bounds__(256) void k_count(const int* __restrict__ ei,
                                               int* __restrict__ deg,
                                               int* __restrict__ pos) {
    int e = blockIdx.x * 256 + threadIdx.x;
    if (e >= NE) return;
    int d = ei[NE + e];
    pos[e] = atomicAdd(&deg[d], 1);
}

__global__ __launch_bounds__(256) void k_scan1(const int* __restrict__ deg,
                                               int* __restrict__ bsum) {
    __shared__ int s[256];
    int i = blockIdx.x * 256 + threadIdx.x;
    s[threadIdx.x] = (i < NN) ? deg[i] : 0;
    __syncthreads();
    for (int o = 128; o > 0; o >>= 1) {
        if (threadIdx.x < o) s[threadIdx.x] += s[threadIdx.x + o];
        __syncthreads();
    }
    if (threadIdx.x == 0) bsum[blockIdx.x] = s[0];
}

__global__ __launch_bounds__(256) void k_scan2(int* __restrict__ bsum, int nb) {
    __shared__ int s[256];
    int t = threadIdx.x;
    int v = (t < nb) ? bsum[t] : 0;
    s[t] = v;
    __syncthreads();
    for (int o = 1; o < 256; o <<= 1) {
        int u = (t >= o) ? s[t - o] : 0;
        __syncthreads();
        s[t] += u;
        __syncthreads();
    }
    if (t < nb) bsum[t] = s[t] - v;  // exclusive
}

__global__ __launch_bounds__(256) void k_scan3(const int* __restrict__ deg,
                                               const int* __restrict__ bsum,
                                               int* __restrict__ row_start) {
    __shared__ int s[256];
    int t = threadIdx.x;
    int i = blockIdx.x * 256 + t;
    int v = (i < NN) ? deg[i] : 0;
    s[t] = v;
    __syncthreads();
    for (int o = 1; o < 256; o <<= 1) {
        int u = (t >= o) ? s[t - o] : 0;
        __syncthreads();
        s[t] += u;
        __syncthreads();
    }
    if (i < NN) row_start[i] = bsum[blockIdx.x] + s[t] - v;
    if (i == 0) row_start[NN] = NE;
}

__global__ __launch_bounds__(256) void k_scatter(const int* __restrict__ ei,
                                                 const int* __restrict__ row_start,
                                                 const int* __restrict__ pos,
                                                 int* __restrict__ csr) {
    int e = blockIdx.x * 256 + threadIdx.x;
    if (e >= NE) return;
    int s = ei[e];
    int d = ei[NE + e];
    csr[row_start[d] + pos[e]] = s;
}

// -------- layer-1 gather: softmax-aggregate + bias + ELU + linear2 + attn coefs --------
__global__ __launch_bounds__(256) void k_gather1(const int* __restrict__ csr,
                                                 const int* __restrict__ row_start,
                                                 const float* __restrict__ aS,
                                                 const float* __restrict__ aD,
                                                 const __half* __restrict__ h1h,
                                                 const float* __restrict__ b1,
                                                 const float* __restrict__ W2,
                                                 const float* __restrict__ attS2,
                                                 const float* __restrict__ attD2,
                                                 float* __restrict__ h2,
                                                 float* __restrict__ aS2,
                                                 float* __restrict__ aD2) {
    const int n    = (blockIdx.x * 256 + threadIdx.x) >> 6;  // grid exact
    const int lane = threadIdx.x & 63;
    const int h    = lane >> 3;

    const float aDd = aD[n * 8 + h];
    const int e0 = row_start[n], e1 = row_start[n + 1];

    float acc = 0.f, den = 0.f;
    for (int base = e0; base < e1; base += 64) {
        int cnt = min(64, e1 - base);
        int sv = (base + lane < e1) ? csr[base + lane] : 0;
        for (int i = 0; i < cnt; ++i) {
            int s = __shfl(sv, i, 64);
            float ev = aS[s * 8 + h] + aDd;
            ev = ev > 0.f ? ev : NEG * ev;
            float ex = __expf(ev);
            den += ex;
            acc += ex * __half2float(h1h[s * 64 + lane]);
        }
    }
    // self-loop
    {
        float ev = aS[n * 8 + h] + aDd;
        ev = ev > 0.f ? ev : NEG * ev;
        float ex = __expf(ev);
        den += ex;
        acc += ex * __half2float(h1h[n * 64 + lane]);
    }
    float v = acc / fmaxf(den, 1e-16f) + b1[lane];
    v = v > 0.f ? v : (__expf(v) - 1.f);   // ELU

    float p0 = v * W2[lane * 2 + 0];
    float p1 = v * W2[lane * 2 + 1];
#pragma unroll
    for (int o = 1; o < 64; o <<= 1) {
        p0 += __shfl_xor(p0, o, 64);
        p1 += __shfl_xor(p1, o, 64);
    }
    if (lane == 0) {
        h2[n * 2 + 0] = p0;
        h2[n * 2 + 1] = p1;
        aS2[n] = p0 * attS2[0] + p1 * attS2[1];
        aD2[n] = p0 * attD2[0] + p1 * attD2[1];
    }
}

// -------- layer-2 gather + graph pool --------
__global__ __launch_bounds__(256) void k_gather2(const int* __restrict__ csr,
                                                 const int* __restrict__ row_start,
                                                 const float* __restrict__ aS2,
                                                 const float* __restrict__ aD2,
                                                 const float* __restrict__ h2,
                                                 const int* __restrict__ batch,
                                                 const float* __restrict__ b2,
                                                 float* __restrict__ out) {
    const int n    = (blockIdx.x * 256 + threadIdx.x) >> 6;
    const int lane = threadIdx.x & 63;

    const float aDd = aD2[n];
    const int e0 = row_start[n], e1 = row_start[n + 1];

    float den = 0.f, p0 = 0.f, p1 = 0.f;
    for (int e = e0 + lane; e < e1; e += 64) {
        int s = csr[e];
        float ev = aS2[s] + aDd;
        ev = ev > 0.f ? ev : NEG * ev;
        float ex = __expf(ev);
        den += ex;
        p0 += ex * h2[s * 2 + 0];
        p1 += ex * h2[s * 2 + 1];
    }
#pragma unroll
    for (int o = 1; o < 64; o <<= 1) {
        den += __shfl_xor(den, o, 64);
        p0  += __shfl_xor(p0, o, 64);
        p1  += __shfl_xor(p1, o, 64);
    }
    if (lane == 0) {
        // self-loop
        float ev = aS2[n] + aDd;
        ev = ev > 0.f ? ev : NEG * ev;
        float ex = __expf(ev);
        den += ex;
        p0  += ex * h2[n * 2 + 0];
        p1  += ex * h2[n * 2 + 1];

        float inv = 1.f / fmaxf(den, 1e-16f);
        int g = batch[n];
        atomicAdd(&out[g * 2 + 0], p0 * inv + b2[0]);
        atomicAdd(&out[g * 2 + 1], p1 * inv + b2[1]);
    }
}

extern "C" void kernel_launch(void* const* d_in, const int* in_sizes, int n_in,
                              void* d_out, int out_size, void* d_ws, size_t ws_size,
                              hipStream_t stream) {
    const float* x     = (const float*)d_in[0];
    const int*   ei    = (const int*)d_in[1];
    const int*   batch = (const int*)d_in[2];
    const float* W1    = (const float*)d_in[3];
    const float* attS1 = (const float*)d_in[4];
    const float* attD1 = (const float*)d_in[5];
    const float* b1    = (const float*)d_in[6];
    const float* W2    = (const float*)d_in[7];
    const float* attS2 = (const float*)d_in[8];
    const float* attD2 = (const float*)d_in[9];
    const float* b2    = (const float*)d_in[10];
    float* out = (float*)d_out;

    float* ws  = (float*)d_ws;
    __half* h1h = (__half*)ws;
    float* aS1 = ws + (size_t)NN * 32;
    float* aD1 = ws + (size_t)NN * 40;
    float* h2  = ws + (size_t)NN * 48;
    float* aS2 = ws + (size_t)NN * 50;
    float* aD2 = ws + (size_t)NN * 51;
    int*   deg       = (int*)(ws + (size_t)NN * 52);
    int*   row_start = (int*)(ws + (size_t)NN * 53);
    int*   bsum      = (int*)(ws + (size_t)NN * 54 + 64);
    int*   pos       = (int*)(ws + (size_t)NN * 55);
    int*   csr       = (int*)(ws + (size_t)NN * 55) + NE;

    const int NB_SCAN = (NN + 255) / 256;  // 196

    k_zero<<<(NN + NG * 2 + 255) / 256, 256, 0, stream>>>(deg, out);
    k_linear1<<<NN / 4, 256, 0, stream>>>(x, W1, attS1, attD1, h1h, aS1, aD1);
    k_count<<<(NE + 255) / 256, 256, 0, stream>>>(ei, deg, pos);
    k_scan1<<<NB_SCAN, 256, 0, stream>>>(deg, bsum);
    k_scan2<<<1, 256, 0, stream>>>(bsum, NB_SCAN);
    k_scan3<<<NB_SCAN, 256, 0, stream>>>(deg, bsum, row_start);
    k_scatter<<<(NE + 255) / 256, 256, 0, stream>>>(ei, row_start, pos, csr);
    k_gather1<<<NN / 4, 256, 0, stream>>>(csr, row_start, aS1, aD1, h1h, b1, W2,
                                          attS2, attD2, h2, aS2, aD2);
    k_gather2<<<NN / 4, 256, 0, stream>>>(csr, row_start, aS2, aD2, h2, batch, b2, out);
}

// Round 4
// 300.374 us; speedup vs baseline: 2.7762x; 1.1843x over previous
//
#include <hip/hip_runtime.h>
#include <hip/hip_fp16.h>

#define NN 50000
#define NE 1600000
#define NG 512
#define NEG 0.2f

#define NB_LIN (NN / 4)            // 12500
#define NB_CNT ((NE + 255) / 256)  // 6250

// ---------------- workspace layout (4-byte units) ----------------
// h1h      : [NN*64] half = NN*32 f   off 0
// aS1      : [NN*8]  f                off NN*32
// aD1      : [NN*8]  f                off NN*40
// h2       : [NN*2]  f                off NN*48
// aS2      : [NN]    f                off NN*50
// aD2      : [NN]    f                off NN*51
// deg      : [NN]    i                off NN*52   <- zeroed each call
// row_start: [NN+1]  i                off NN*53
// bsum     : [256]   i                off NN*54 + 64
// pos      : [NE]    i                off NN*55
// csr      : [NE]    i                off NN*55 + NE

__global__ __launch_bounds__(256) void k_zero(int* __restrict__ deg,
                                              float* __restrict__ out) {
    int i = blockIdx.x * 256 + threadIdx.x;
    if (i < NN) deg[i] = 0;
    else if (i < NN + NG * 2) out[i - NN] = 0.f;
}

// union kernel: blocks [0, NB_LIN) do linear1; blocks [NB_LIN, ..) do edge count
__global__ __launch_bounds__(256) void k_lin_count(const float* __restrict__ x,
                                                   const float* __restrict__ W1,
                                                   const float* __restrict__ attS,
                                                   const float* __restrict__ attD,
                                                   __half* __restrict__ h1h,
                                                   float* __restrict__ aS,
                                                   float* __restrict__ aD,
                                                   const int* __restrict__ ei,
                                                   int* __restrict__ deg,
                                                   int* __restrict__ pos) {
    if (blockIdx.x < NB_LIN) {
        __shared__ float xs[4][136];
        const int sub = threadIdx.x >> 6;
        const int j   = threadIdx.x & 63;
        const int n   = blockIdx.x * 4 + sub;   // NN % 4 == 0

        for (int k = j; k < 133; k += 64) xs[sub][k] = x[n * 133 + k];
        __syncthreads();

        float acc = 0.f;
#pragma unroll 7
        for (int k = 0; k < 133; ++k) acc += xs[sub][k] * W1[k * 64 + j];

        h1h[n * 64 + j] = __float2half(acc);

        const int head = j >> 3, c = j & 7;
        float ps = acc * attS[head * 8 + c];
        float pd = acc * attD[head * 8 + c];
#pragma unroll
        for (int o = 1; o < 8; o <<= 1) {
            ps += __shfl_xor(ps, o, 64);
            pd += __shfl_xor(pd, o, 64);
        }
        if (c == 0) {
            aS[n * 8 + head] = ps;
            aD[n * 8 + head] = pd;
        }
    } else {
        int e = (blockIdx.x - NB_LIN) * 256 + threadIdx.x;
        if (e < NE) {
            int d = ei[NE + e];
            pos[e] = atomicAdd(&deg[d], 1);
        }
    }
}

__global__ __launch_bounds__(256) void k_scan1(const int* __restrict__ deg,
                                               int* __restrict__ bsum) {
    __shared__ int s[256];
    int i = blockIdx.x * 256 + threadIdx.x;
    s[threadIdx.x] = (i < NN) ? deg[i] : 0;
    __syncthreads();
    for (int o = 128; o > 0; o >>= 1) {
        if (threadIdx.x < o) s[threadIdx.x] += s[threadIdx.x + o];
        __syncthreads();
    }
    if (threadIdx.x == 0) bsum[blockIdx.x] = s[0];
}

__global__ __launch_bounds__(256) void k_scan2(int* __restrict__ bsum, int nb) {
    __shared__ int s[256];
    int t = threadIdx.x;
    int v = (t < nb) ? bsum[t] : 0;
    s[t] = v;
    __syncthreads();
    for (int o = 1; o < 256; o <<= 1) {
        int u = (t >= o) ? s[t - o] : 0;
        __syncthreads();
        s[t] += u;
        __syncthreads();
    }
    if (t < nb) bsum[t] = s[t] - v;  // exclusive
}

__global__ __launch_bounds__(256) void k_scan3(const int* __restrict__ deg,
                                               const int* __restrict__ bsum,
                                               int* __restrict__ row_start) {
    __shared__ int s[256];
    int t = threadIdx.x;
    int i = blockIdx.x * 256 + t;
    int v = (i < NN) ? deg[i] : 0;
    s[t] = v;
    __syncthreads();
    for (int o = 1; o < 256; o <<= 1) {
        int u = (t >= o) ? s[t - o] : 0;
        __syncthreads();
        s[t] += u;
        __syncthreads();
    }
    if (i < NN) row_start[i] = bsum[blockIdx.x] + s[t] - v;
    if (i == 0) row_start[NN] = NE;
}

__global__ __launch_bounds__(256) void k_scatter(const int* __restrict__ ei,
                                                 const int* __restrict__ row_start,
                                                 const int* __restrict__ pos,
                                                 int* __restrict__ csr) {
    int e = blockIdx.x * 256 + threadIdx.x;
    if (e >= NE) return;
    int s = ei[e];
    int d = ei[NE + e];
    csr[row_start[d] + pos[e]] = s;
}

// -------- layer-1 gather, two-phase --------
// phase 1 (per 64-edge batch): 8 passes, 64 lanes = (8 edges x 8 heads),
//   compute exp-weights edge-parallel, stage to LDS.
// phase 2: serial over edges, 64 lanes = 64 output cols, fma-aggregate.
__global__ __launch_bounds__(256) void k_gather1(const int* __restrict__ csr,
                                                 const int* __restrict__ row_start,
                                                 const float* __restrict__ aS,
                                                 const float* __restrict__ aD,
                                                 const __half* __restrict__ h1h,
                                                 const float* __restrict__ b1,
                                                 const float* __restrict__ W2,
                                                 const float* __restrict__ attS2,
                                                 const float* __restrict__ attD2,
                                                 float* __restrict__ h2,
                                                 float* __restrict__ aS2,
                                                 float* __restrict__ aD2) {
    __shared__ float exs[4][64 * 8];
    __shared__ int   svs[4][64];

    const int sub  = threadIdx.x >> 6;
    const int lane = threadIdx.x & 63;
    const int n    = (blockIdx.x * 256 + threadIdx.x) >> 6;  // grid exact
    const int h    = lane >> 3;   // head owned in phase 2 (col = lane)
    const int hp   = lane & 7;    // head owned in phase 1
    const int ebl  = lane >> 3;   // edge-within-pass-group in phase 1

    const float aDhp = aD[n * 8 + hp];
    const int e0 = row_start[n], e1 = row_start[n + 1];

    float acc = 0.f, den = 0.f;
    for (int base = e0; base < e1; base += 64) {
        const int cnt = min(64, e1 - base);
        int sv = (base + lane < e1) ? csr[base + lane] : n;
        svs[sub][lane] = sv;

        // phase 1: edge-parallel exp weights
#pragma unroll
        for (int p = 0; p < 8; ++p) {
            int eb = p * 8 + ebl;
            int s  = svs[sub][eb];
            float ev = aS[s * 8 + hp] + aDhp;
            ev = fmaxf(ev, NEG * ev);            // leaky relu (NEG > 0)
            float ex = __expf(ev);
            if (eb >= cnt) ex = 0.f;             // zero-pad tail
            exs[sub][eb * 8 + hp] = ex;
        }

        // phase 2: column-parallel aggregation, unroll 8 (pads contribute 0)
        const int cnt8 = (cnt + 7) & ~7;
        for (int eb = 0; eb < cnt8; eb += 8) {
#pragma unroll
            for (int k = 0; k < 8; ++k) {
                int   s  = svs[sub][eb + k];
                float ex = exs[sub][(eb + k) * 8 + h];
                den += ex;
                acc = fmaf(ex, __half2float(h1h[s * 64 + lane]), acc);
            }
        }
    }
    // self-loop
    {
        float ev = aS[n * 8 + h] + aD[n * 8 + h];
        ev = fmaxf(ev, NEG * ev);
        float ex = __expf(ev);
        den += ex;
        acc = fmaf(ex, __half2float(h1h[n * 64 + lane]), acc);
    }
    float v = acc / fmaxf(den, 1e-16f) + b1[lane];
    v = v > 0.f ? v : (__expf(v) - 1.f);   // ELU

    float p0 = v * W2[lane * 2 + 0];
    float p1 = v * W2[lane * 2 + 1];
#pragma unroll
    for (int o = 1; o < 64; o <<= 1) {
        p0 += __shfl_xor(p0, o, 64);
        p1 += __shfl_xor(p1, o, 64);
    }
    if (lane == 0) {
        h2[n * 2 + 0] = p0;
        h2[n * 2 + 1] = p1;
        aS2[n] = p0 * attS2[0] + p1 * attS2[1];
        aD2[n] = p0 * attD2[0] + p1 * attD2[1];
    }
}

// -------- layer-2 gather + graph pool --------
__global__ __launch_bounds__(256) void k_gather2(const int* __restrict__ csr,
                                                 const int* __restrict__ row_start,
                                                 const float* __restrict__ aS2,
                                                 const float* __restrict__ aD2,
                                                 const float* __restrict__ h2,
                                                 const int* __restrict__ batch,
                                                 const float* __restrict__ b2,
                                                 float* __restrict__ out) {
    const int n    = (blockIdx.x * 256 + threadIdx.x) >> 6;
    const int lane = threadIdx.x & 63;

    const float aDd = aD2[n];
    const int e0 = row_start[n], e1 = row_start[n + 1];

    float den = 0.f, p0 = 0.f, p1 = 0.f;
    for (int e = e0 + lane; e < e1; e += 64) {
        int s = csr[e];
        float ev = aS2[s] + aDd;
        ev = fmaxf(ev, NEG * ev);
        float ex = __expf(ev);
        den += ex;
        p0 += ex * h2[s * 2 + 0];
        p1 += ex * h2[s * 2 + 1];
    }
#pragma unroll
    for (int o = 1; o < 64; o <<= 1) {
        den += __shfl_xor(den, o, 64);
        p0  += __shfl_xor(p0, o, 64);
        p1  += __shfl_xor(p1, o, 64);
    }
    if (lane == 0) {
        // self-loop
        float ev = aS2[n] + aDd;
        ev = fmaxf(ev, NEG * ev);
        float ex = __expf(ev);
        den += ex;
        p0  += ex * h2[n * 2 + 0];
        p1  += ex * h2[n * 2 + 1];

        float inv = 1.f / fmaxf(den, 1e-16f);
        int g = batch[n];
        atomicAdd(&out[g * 2 + 0], p0 * inv + b2[0]);
        atomicAdd(&out[g * 2 + 1], p1 * inv + b2[1]);
    }
}

extern "C" void kernel_launch(void* const* d_in, const int* in_sizes, int n_in,
                              void* d_out, int out_size, void* d_ws, size_t ws_size,
                              hipStream_t stream) {
    const float* x     = (const float*)d_in[0];
    const int*   ei    = (const int*)d_in[1];
    const int*   batch = (const int*)d_in[2];
    const float* W1    = (const float*)d_in[3];
    const float* attS1 = (const float*)d_in[4];
    const float* attD1 = (const float*)d_in[5];
    const float* b1    = (const float*)d_in[6];
    const float* W2    = (const float*)d_in[7];
    const float* attS2 = (const float*)d_in[8];
    const float* attD2 = (const float*)d_in[9];
    const float* b2    = (const float*)d_in[10];
    float* out = (float*)d_out;

    float* ws  = (float*)d_ws;
    __half* h1h = (__half*)ws;
    float* aS1 = ws + (size_t)NN * 32;
    float* aD1 = ws + (size_t)NN * 40;
    float* h2  = ws + (size_t)NN * 48;
    float* aS2 = ws + (size_t)NN * 50;
    float* aD2 = ws + (size_t)NN * 51;
    int*   deg       = (int*)(ws + (size_t)NN * 52);
    int*   row_start = (int*)(ws + (size_t)NN * 53);
    int*   bsum      = (int*)(ws + (size_t)NN * 54 + 64);
    int*   pos       = (int*)(ws + (size_t)NN * 55);
    int*   csr       = (int*)(ws + (size_t)NN * 55) + NE;

    const int NB_SCAN = (NN + 255) / 256;  // 196

    k_zero<<<(NN + NG * 2 + 255) / 256, 256, 0, stream>>>(deg, out);
    k_lin_count<<<NB_LIN + NB_CNT, 256, 0, stream>>>(x, W1, attS1, attD1, h1h,
                                                     aS1, aD1, ei, deg, pos);
    k_scan1<<<NB_SCAN, 256, 0, stream>>>(deg, bsum);
    k_scan2<<<1, 256, 0, stream>>>(bsum, NB_SCAN);
    k_scan3<<<NB_SCAN, 256, 0, stream>>>(deg, bsum, row_start);
    k_scatter<<<(NE + 255) / 256, 256, 0, stream>>>(ei, row_start, pos, csr);
    k_gather1<<<NN / 4, 256, 0, stream>>>(csr, row_start, aS1, aD1, h1h, b1, W2,
                                          attS2, attD2, h2, aS2, aD2);
    k_gather2<<<NN / 4, 256, 0, stream>>>(csr, row_start, aS2, aD2, h2, batch, b2, out);
}

// Round 5
// 252.328 us; speedup vs baseline: 3.3048x; 1.1904x over previous
//
#include <hip/hip_runtime.h>
#include <hip/hip_fp16.h>

#define NN 50000
#define NE 1600000
#define NG 512
#define NEG 0.2f

#define NBKT 391            // ceil(50000/128) buckets of 128 dst nodes
#define CHUNK 4096          // edges per binscatter block
#define CAP 8192            // max edges per bucket (avg 4092, ~64 sigma margin)

// ---------------- workspace layout (4-byte words) ----------------
// h1h   [NN*64] half        @ 0
// aS1   [NN*8]  f           @ NN*32
// aD1   [NN*8]  f           @ NN*40
// h2    [NN*2]  f           @ NN*48
// aS2   [NN]    f           @ NN*50
// aD2   [NN]    f           @ NN*51
// row_start [NN+1] i        @ NN*52
// bucket_count [400] i      @ NN*53 + 64   <- zeroed each call
// bucket_base  [400] i      @ NN*53 + 464
// bucket_cursor[400] i      @ NN*53 + 864
// binned [NE]  u32          @ NN*54
// csr    [NE]  u16          @ NN*54 + NE
// total ~ 20.4 MB

__global__ __launch_bounds__(256) void k_zero(int* __restrict__ bcount,
                                              float* __restrict__ out) {
    int i = blockIdx.x * 256 + threadIdx.x;
    if (i < NBKT) bcount[i] = 0;
    else if (i < NBKT + NG * 2) out[i - NBKT] = 0.f;
}

// per-node: h1 = x @ W1 (stored fp16), plus per-head attention coefficients
__global__ __launch_bounds__(256) void k_linear1(const float* __restrict__ x,
                                                 const float* __restrict__ W1,
                                                 const float* __restrict__ attS,
                                                 const float* __restrict__ attD,
                                                 __half* __restrict__ h1h,
                                                 float* __restrict__ aS,
                                                 float* __restrict__ aD) {
    __shared__ float xs[4][136];
    const int sub = threadIdx.x >> 6;
    const int j   = threadIdx.x & 63;
    const int n   = blockIdx.x * 4 + sub;   // NN % 4 == 0

    for (int k = j; k < 133; k += 64) xs[sub][k] = x[n * 133 + k];
    __syncthreads();

    float acc = 0.f;
#pragma unroll 7
    for (int k = 0; k < 133; ++k) acc += xs[sub][k] * W1[k * 64 + j];

    h1h[n * 64 + j] = __float2half(acc);

    const int head = j >> 3, c = j & 7;
    float ps = acc * attS[head * 8 + c];
    float pd = acc * attD[head * 8 + c];
#pragma unroll
    for (int o = 1; o < 8; o <<= 1) {
        ps += __shfl_xor(ps, o, 64);
        pd += __shfl_xor(pd, o, 64);
    }
    if (c == 0) {
        aS[n * 8 + head] = ps;
        aD[n * 8 + head] = pd;
    }
}

// -------- binned CSR build --------
__global__ __launch_bounds__(256) void k_bincount(const int* __restrict__ ei,
                                                  int* __restrict__ bcount) {
    __shared__ int hist[NBKT];
    for (int i = threadIdx.x; i < NBKT; i += 256) hist[i] = 0;
    __syncthreads();
    for (int e = blockIdx.x * 256 + threadIdx.x; e < NE; e += 256 * 256)
        atomicAdd(&hist[ei[NE + e] >> 7], 1);
    __syncthreads();
    for (int i = threadIdx.x; i < NBKT; i += 256) {
        int v = hist[i];
        if (v) atomicAdd(&bcount[i], v);
    }
}

__global__ __launch_bounds__(512) void k_bucketscan(const int* __restrict__ bcount,
                                                    int* __restrict__ bbase,
                                                    int* __restrict__ bcursor,
                                                    int* __restrict__ row_start) {
    __shared__ int s[512];
    const int t = threadIdx.x;
    int v = (t < NBKT) ? bcount[t] : 0;
    s[t] = v;
    __syncthreads();
    for (int o = 1; o < 512; o <<= 1) {
        int u = (t >= o) ? s[t - o] : 0;
        __syncthreads();
        s[t] += u;
        __syncthreads();
    }
    if (t < NBKT) {
        int ex = s[t] - v;   // exclusive
        bbase[t]   = ex;
        bcursor[t] = ex;
    }
    if (t == 0) {
        bbase[NBKT]   = NE;
        row_start[NN] = NE;
    }
}

__global__ __launch_bounds__(256) void k_binscatter(const int* __restrict__ ei,
                                                    int* __restrict__ bcursor,
                                                    unsigned* __restrict__ binned) {
    __shared__ int hist[NBKT];
    __shared__ int basel[NBKT];
    const int t = threadIdx.x;
    const int estart = blockIdx.x * CHUNK;

    for (int i = t; i < NBKT; i += 256) hist[i] = 0;
    __syncthreads();

    unsigned pk[16];
    int br[16];
#pragma unroll
    for (int i = 0; i < 16; ++i) {
        int e = estart + t + i * 256;
        if (e < NE) {
            int s = ei[e];
            int d = ei[NE + e];
            int b = d >> 7;
            int r = atomicAdd(&hist[b], 1);
            pk[i] = ((unsigned)s << 7) | (unsigned)(d & 127);
            br[i] = (r << 9) | b;         // r<4096 (13b), b<512 (9b)
        } else {
            br[i] = -1;
        }
    }
    __syncthreads();
    for (int i = t; i < NBKT; i += 256)
        basel[i] = hist[i] ? atomicAdd(&bcursor[i], hist[i]) : 0;
    __syncthreads();
#pragma unroll
    for (int i = 0; i < 16; ++i) {
        if (br[i] >= 0) {
            int b = br[i] & 511;
            int r = br[i] >> 9;
            binned[basel[b] + r] = pk[i];
        }
    }
}

__global__ __launch_bounds__(256) void k_buildcsr(const unsigned* __restrict__ binned,
                                                  const int* __restrict__ bbase,
                                                  int* __restrict__ row_start,
                                                  unsigned short* __restrict__ csr) {
    __shared__ unsigned edg[CAP];
    __shared__ unsigned short csrl[CAP];
    __shared__ int deg[128], scn[128], cur[128];

    const int b = blockIdx.x, t = threadIdx.x;
    const int ebase = bbase[b];
    const int ecnt  = min(bbase[b + 1] - ebase, CAP);
    const int nbase = b << 7;
    const int ncnt  = min(128, NN - nbase);

    for (int i = t; i < ecnt; i += 256) edg[i] = binned[ebase + i];
    if (t < 128) deg[t] = 0;
    __syncthreads();
    for (int i = t; i < ecnt; i += 256) atomicAdd(&deg[edg[i] & 127], 1);
    __syncthreads();
    if (t < 128) scn[t] = deg[t];
    __syncthreads();
    for (int o = 1; o < 128; o <<= 1) {
        int v = (t < 128 && t >= o) ? scn[t - o] : 0;
        __syncthreads();
        if (t < 128) scn[t] += v;
        __syncthreads();
    }
    if (t < 128) {
        int ex = scn[t] - deg[t];   // exclusive
        cur[t] = ex;
        if (t < ncnt) row_start[nbase + t] = ebase + ex;
    }
    __syncthreads();
    for (int i = t; i < ecnt; i += 256) {
        unsigned pk = edg[i];
        int pos = atomicAdd(&cur[pk & 127], 1);
        csrl[pos] = (unsigned short)(pk >> 7);
    }
    __syncthreads();
    for (int i = t; i < ecnt; i += 256) csr[ebase + i] = csrl[i];
}

// -------- layer-1 gather, two-phase --------
__global__ __launch_bounds__(256) void k_gather1(const unsigned short* __restrict__ csr,
                                                 const int* __restrict__ row_start,
                                                 const float* __restrict__ aS,
                                                 const float* __restrict__ aD,
                                                 const __half* __restrict__ h1h,
                                                 const float* __restrict__ b1,
                                                 const float* __restrict__ W2,
                                                 const float* __restrict__ attS2,
                                                 const float* __restrict__ attD2,
                                                 float* __restrict__ h2,
                                                 float* __restrict__ aS2,
                                                 float* __restrict__ aD2) {
    __shared__ float exs[4][64 * 8];
    __shared__ int   svs[4][64];

    const int sub  = threadIdx.x >> 6;
    const int lane = threadIdx.x & 63;
    const int n    = (blockIdx.x * 256 + threadIdx.x) >> 6;  // grid exact
    const int h    = lane >> 3;   // head owned in phase 2 (col = lane)
    const int hp   = lane & 7;    // head owned in phase 1
    const int ebl  = lane >> 3;   // edge-within-pass in phase 1

    const float aDhp = aD[n * 8 + hp];
    const int e0 = row_start[n], e1 = row_start[n + 1];

    float acc = 0.f, den = 0.f;
    for (int base = e0; base < e1; base += 64) {
        const int cnt = min(64, e1 - base);
        int sv = (base + lane < e1) ? (int)csr[base + lane] : n;
        svs[sub][lane] = sv;

        // phase 1: edge-parallel exp weights
#pragma unroll
        for (int p = 0; p < 8; ++p) {
            int eb = p * 8 + ebl;
            int s  = svs[sub][eb];
            float ev = aS[s * 8 + hp] + aDhp;
            ev = fmaxf(ev, NEG * ev);            // leaky relu
            float ex = __expf(ev);
            if (eb >= cnt) ex = 0.f;             // zero-pad tail
            exs[sub][eb * 8 + hp] = ex;
        }

        // phase 2: column-parallel aggregation, unroll 8 (pads contribute 0)
        const int cnt8 = (cnt + 7) & ~7;
        for (int eb = 0; eb < cnt8; eb += 8) {
#pragma unroll
            for (int k = 0; k < 8; ++k) {
                int   s  = svs[sub][eb + k];
                float ex = exs[sub][(eb + k) * 8 + h];
                den += ex;
                acc = fmaf(ex, __half2float(h1h[s * 64 + lane]), acc);
            }
        }
    }
    // self-loop
    {
        float ev = aS[n * 8 + h] + aD[n * 8 + h];
        ev = fmaxf(ev, NEG * ev);
        float ex = __expf(ev);
        den += ex;
        acc = fmaf(ex, __half2float(h1h[n * 64 + lane]), acc);
    }
    float v = acc / fmaxf(den, 1e-16f) + b1[lane];
    v = v > 0.f ? v : (__expf(v) - 1.f);   // ELU

    float p0 = v * W2[lane * 2 + 0];
    float p1 = v * W2[lane * 2 + 1];
#pragma unroll
    for (int o = 1; o < 64; o <<= 1) {
        p0 += __shfl_xor(p0, o, 64);
        p1 += __shfl_xor(p1, o, 64);
    }
    if (lane == 0) {
        h2[n * 2 + 0] = p0;
        h2[n * 2 + 1] = p1;
        aS2[n] = p0 * attS2[0] + p1 * attS2[1];
        aD2[n] = p0 * attD2[0] + p1 * attD2[1];
    }
}

// -------- layer-2 gather + graph pool --------
__global__ __launch_bounds__(256) void k_gather2(const unsigned short* __restrict__ csr,
                                                 const int* __restrict__ row_start,
                                                 const float* __restrict__ aS2,
                                                 const float* __restrict__ aD2,
                                                 const float* __restrict__ h2,
                                                 const int* __restrict__ batch,
                                                 const float* __restrict__ b2,
                                                 float* __restrict__ out) {
    const int n    = (blockIdx.x * 256 + threadIdx.x) >> 6;
    const int lane = threadIdx.x & 63;

    const float aDd = aD2[n];
    const int e0 = row_start[n], e1 = row_start[n + 1];

    float den = 0.f, p0 = 0.f, p1 = 0.f;
    for (int e = e0 + lane; e < e1; e += 64) {
        int s = csr[e];
        float ev = aS2[s] + aDd;
        ev = fmaxf(ev, NEG * ev);
        float ex = __expf(ev);
        den += ex;
        p0 += ex * h2[s * 2 + 0];
        p1 += ex * h2[s * 2 + 1];
    }
#pragma unroll
    for (int o = 1; o < 64; o <<= 1) {
        den += __shfl_xor(den, o, 64);
        p0  += __shfl_xor(p0, o, 64);
        p1  += __shfl_xor(p1, o, 64);
    }
    if (lane == 0) {
        // self-loop
        float ev = aS2[n] + aDd;
        ev = fmaxf(ev, NEG * ev);
        float ex = __expf(ev);
        den += ex;
        p0  += ex * h2[n * 2 + 0];
        p1  += ex * h2[n * 2 + 1];

        float inv = 1.f / fmaxf(den, 1e-16f);
        int g = batch[n];
        atomicAdd(&out[g * 2 + 0], p0 * inv + b2[0]);
        atomicAdd(&out[g * 2 + 1], p1 * inv + b2[1]);
    }
}

extern "C" void kernel_launch(void* const* d_in, const int* in_sizes, int n_in,
                              void* d_out, int out_size, void* d_ws, size_t ws_size,
                              hipStream_t stream) {
    const float* x     = (const float*)d_in[0];
    const int*   ei    = (const int*)d_in[1];
    const int*   batch = (const int*)d_in[2];
    const float* W1    = (const float*)d_in[3];
    const float* attS1 = (const float*)d_in[4];
    const float* attD1 = (const float*)d_in[5];
    const float* b1    = (const float*)d_in[6];
    const float* W2    = (const float*)d_in[7];
    const float* attS2 = (const float*)d_in[8];
    const float* attD2 = (const float*)d_in[9];
    const float* b2    = (const float*)d_in[10];
    float* out = (float*)d_out;

    int* ws = (int*)d_ws;
    __half* h1h = (__half*)ws;
    float* aS1 = (float*)(ws + (size_t)NN * 32);
    float* aD1 = (float*)(ws + (size_t)NN * 40);
    float* h2  = (float*)(ws + (size_t)NN * 48);
    float* aS2 = (float*)(ws + (size_t)NN * 50);
    float* aD2 = (float*)(ws + (size_t)NN * 51);
    int* row_start = ws + (size_t)NN * 52;
    int* bcount    = ws + (size_t)NN * 53 + 64;
    int* bbase     = ws + (size_t)NN * 53 + 464;
    int* bcursor   = ws + (size_t)NN * 53 + 864;
    unsigned* binned     = (unsigned*)(ws + (size_t)NN * 54);
    unsigned short* csr  = (unsigned short*)(ws + (size_t)NN * 54 + NE);

    k_zero<<<(NBKT + NG * 2 + 255) / 256, 256, 0, stream>>>(bcount, out);
    k_linear1<<<NN / 4, 256, 0, stream>>>(x, W1, attS1, attD1, h1h, aS1, aD1);
    k_bincount<<<256, 256, 0, stream>>>(ei, bcount);
    k_bucketscan<<<1, 512, 0, stream>>>(bcount, bbase, bcursor, row_start);
    k_binscatter<<<(NE + CHUNK - 1) / CHUNK, 256, 0, stream>>>(ei, bcursor, binned);
    k_buildcsr<<<NBKT, 256, 0, stream>>>(binned, bbase, row_start, csr);
    k_gather1<<<NN / 4, 256, 0, stream>>>(csr, row_start, aS1, aD1, h1h, b1, W2,
                                          attS2, attD2, h2, aS2, aD2);
    k_gather2<<<NN / 4, 256, 0, stream>>>(csr, row_start, aS2, aD2, h2, batch, b2, out);
}

// Round 6
// 163.530 us; speedup vs baseline: 5.0993x; 1.5430x over previous
//
#include <hip/hip_runtime.h>
#include <hip/hip_fp16.h>

#define NN 50000
#define NE 1600000
#define NG 512
#define NEG 0.2f

#define NBKT 391            // ceil(50000/128) buckets of 128 dst nodes
#define CHUNK 4096          // edges per binscatter block
#define CAP 8192            // max edges per bucket (avg 4092, ~64 sigma margin)
#define NSLOT 32            // LDS graph-pool slots per block

// ---------------- workspace layout (4-byte words) ----------------
// h1h   [NN*64] half        @ 0
// aS1   [NN*8]  f           @ NN*32
// aD1   [NN*8]  f           @ NN*40
// node4 [NN*4]  f (h2_0,h2_1,aS2,aD2) @ NN*48
// row_start [NN+1] i        @ NN*52
// bucket_count [400] i      @ NN*53 + 64   <- zeroed each call
// bucket_base  [400] i      @ NN*53 + 464
// bucket_cursor[400] i      @ NN*53 + 864
// binned [NE]  u32          @ NN*54
// csr    [NE]  u16          @ NN*54 + NE

__global__ __launch_bounds__(256) void k_zero(int* __restrict__ bcount,
                                              float* __restrict__ out) {
    int i = blockIdx.x * 256 + threadIdx.x;
    if (i < NBKT) bcount[i] = 0;
    else if (i < NBKT + NG * 2) out[i - NBKT] = 0.f;
}

// per-node: h1 = x @ W1 (stored fp16), plus per-head attention coefficients
__global__ __launch_bounds__(256) void k_linear1(const float* __restrict__ x,
                                                 const float* __restrict__ W1,
                                                 const float* __restrict__ attS,
                                                 const float* __restrict__ attD,
                                                 __half* __restrict__ h1h,
                                                 float* __restrict__ aS,
                                                 float* __restrict__ aD) {
    __shared__ float xs[4][136];
    const int sub = threadIdx.x >> 6;
    const int j   = threadIdx.x & 63;
    const int n   = blockIdx.x * 4 + sub;   // NN % 4 == 0

    for (int k = j; k < 133; k += 64) xs[sub][k] = x[n * 133 + k];
    __syncthreads();

    float acc = 0.f;
#pragma unroll 7
    for (int k = 0; k < 133; ++k) acc += xs[sub][k] * W1[k * 64 + j];

    h1h[n * 64 + j] = __float2half(acc);

    const int head = j >> 3, c = j & 7;
    float ps = acc * attS[head * 8 + c];
    float pd = acc * attD[head * 8 + c];
#pragma unroll
    for (int o = 1; o < 8; o <<= 1) {
        ps += __shfl_xor(ps, o, 64);
        pd += __shfl_xor(pd, o, 64);
    }
    if (c == 0) {
        aS[n * 8 + head] = ps;
        aD[n * 8 + head] = pd;
    }
}

// -------- binned CSR build --------
__global__ __launch_bounds__(256) void k_bincount(const int* __restrict__ ei,
                                                  int* __restrict__ bcount) {
    __shared__ int hist[NBKT];
    for (int i = threadIdx.x; i < NBKT; i += 256) hist[i] = 0;
    __syncthreads();
    for (int e = blockIdx.x * 256 + threadIdx.x; e < NE; e += 256 * 256)
        atomicAdd(&hist[ei[NE + e] >> 7], 1);
    __syncthreads();
    for (int i = threadIdx.x; i < NBKT; i += 256) {
        int v = hist[i];
        if (v) atomicAdd(&bcount[i], v);
    }
}

__global__ __launch_bounds__(512) void k_bucketscan(const int* __restrict__ bcount,
                                                    int* __restrict__ bbase,
                                                    int* __restrict__ bcursor,
                                                    int* __restrict__ row_start) {
    __shared__ int s[512];
    const int t = threadIdx.x;
    int v = (t < NBKT) ? bcount[t] : 0;
    s[t] = v;
    __syncthreads();
    for (int o = 1; o < 512; o <<= 1) {
        int u = (t >= o) ? s[t - o] : 0;
        __syncthreads();
        s[t] += u;
        __syncthreads();
    }
    if (t < NBKT) {
        int ex = s[t] - v;   // exclusive
        bbase[t]   = ex;
        bcursor[t] = ex;
    }
    if (t == 0) {
        bbase[NBKT]   = NE;
        row_start[NN] = NE;
    }
}

__global__ __launch_bounds__(256) void k_binscatter(const int* __restrict__ ei,
                                                    int* __restrict__ bcursor,
                                                    unsigned* __restrict__ binned) {
    __shared__ int hist[NBKT];
    __shared__ int basel[NBKT];
    const int t = threadIdx.x;
    const int estart = blockIdx.x * CHUNK;

    for (int i = t; i < NBKT; i += 256) hist[i] = 0;
    __syncthreads();

    unsigned pk[16];
    int br[16];
#pragma unroll
    for (int i = 0; i < 16; ++i) {
        int e = estart + t + i * 256;
        if (e < NE) {
            int s = ei[e];
            int d = ei[NE + e];
            int b = d >> 7;
            int r = atomicAdd(&hist[b], 1);
            pk[i] = ((unsigned)s << 7) | (unsigned)(d & 127);
            br[i] = (r << 9) | b;         // r<4096 (13b), b<512 (9b)
        } else {
            br[i] = -1;
        }
    }
    __syncthreads();
    for (int i = t; i < NBKT; i += 256)
        basel[i] = hist[i] ? atomicAdd(&bcursor[i], hist[i]) : 0;
    __syncthreads();
#pragma unroll
    for (int i = 0; i < 16; ++i) {
        if (br[i] >= 0) {
            int b = br[i] & 511;
            int r = br[i] >> 9;
            binned[basel[b] + r] = pk[i];
        }
    }
}

__global__ __launch_bounds__(256) void k_buildcsr(const unsigned* __restrict__ binned,
                                                  const int* __restrict__ bbase,
                                                  int* __restrict__ row_start,
                                                  unsigned short* __restrict__ csr) {
    __shared__ unsigned edg[CAP];
    __shared__ unsigned short csrl[CAP];
    __shared__ int deg[128], scn[128], cur[128];

    const int b = blockIdx.x, t = threadIdx.x;
    const int ebase = bbase[b];
    const int ecnt  = min(bbase[b + 1] - ebase, CAP);
    const int nbase = b << 7;
    const int ncnt  = min(128, NN - nbase);

    for (int i = t; i < ecnt; i += 256) edg[i] = binned[ebase + i];
    if (t < 128) deg[t] = 0;
    __syncthreads();
    for (int i = t; i < ecnt; i += 256) atomicAdd(&deg[edg[i] & 127], 1);
    __syncthreads();
    if (t < 128) scn[t] = deg[t];
    __syncthreads();
    for (int o = 1; o < 128; o <<= 1) {
        int v = (t < 128 && t >= o) ? scn[t - o] : 0;
        __syncthreads();
        if (t < 128) scn[t] += v;
        __syncthreads();
    }
    if (t < 128) {
        int ex = scn[t] - deg[t];   // exclusive
        cur[t] = ex;
        if (t < ncnt) row_start[nbase + t] = ebase + ex;
    }
    __syncthreads();
    for (int i = t; i < ecnt; i += 256) {
        unsigned pk = edg[i];
        int pos = atomicAdd(&cur[pk & 127], 1);
        csrl[pos] = (unsigned short)(pk >> 7);
    }
    __syncthreads();
    for (int i = t; i < ecnt; i += 256) csr[ebase + i] = csrl[i];
}

// -------- layer-1 gather, two-phase; epilogue packs node4 --------
__global__ __launch_bounds__(256) void k_gather1(const unsigned short* __restrict__ csr,
                                                 const int* __restrict__ row_start,
                                                 const float* __restrict__ aS,
                                                 const float* __restrict__ aD,
                                                 const __half* __restrict__ h1h,
                                                 const float* __restrict__ b1,
                                                 const float* __restrict__ W2,
                                                 const float* __restrict__ attS2,
                                                 const float* __restrict__ attD2,
                                                 float4* __restrict__ node4) {
    __shared__ float exs[4][64 * 8];
    __shared__ int   svs[4][64];

    const int sub  = threadIdx.x >> 6;
    const int lane = threadIdx.x & 63;
    const int n    = (blockIdx.x * 256 + threadIdx.x) >> 6;  // grid exact
    const int h    = lane >> 3;   // head owned in phase 2 (col = lane)
    const int hp   = lane & 7;    // head owned in phase 1
    const int ebl  = lane >> 3;   // edge-within-pass in phase 1

    const float aDhp = aD[n * 8 + hp];
    const int e0 = row_start[n], e1 = row_start[n + 1];

    float acc = 0.f, den = 0.f;
    for (int base = e0; base < e1; base += 64) {
        const int cnt = min(64, e1 - base);
        int sv = (base + lane < e1) ? (int)csr[base + lane] : n;
        svs[sub][lane] = sv;

        // phase 1: edge-parallel exp weights
#pragma unroll
        for (int p = 0; p < 8; ++p) {
            int eb = p * 8 + ebl;
            int s  = svs[sub][eb];
            float ev = aS[s * 8 + hp] + aDhp;
            ev = fmaxf(ev, NEG * ev);            // leaky relu
            float ex = __expf(ev);
            if (eb >= cnt) ex = 0.f;             // zero-pad tail
            exs[sub][eb * 8 + hp] = ex;
        }

        // phase 2: column-parallel aggregation, unroll 8 (pads contribute 0)
        const int cnt8 = (cnt + 7) & ~7;
        for (int eb = 0; eb < cnt8; eb += 8) {
#pragma unroll
            for (int k = 0; k < 8; ++k) {
                int   s  = svs[sub][eb + k];
                float ex = exs[sub][(eb + k) * 8 + h];
                den += ex;
                acc = fmaf(ex, __half2float(h1h[s * 64 + lane]), acc);
            }
        }
    }
    // self-loop
    {
        float ev = aS[n * 8 + h] + aD[n * 8 + h];
        ev = fmaxf(ev, NEG * ev);
        float ex = __expf(ev);
        den += ex;
        acc = fmaf(ex, __half2float(h1h[n * 64 + lane]), acc);
    }
    float v = acc / fmaxf(den, 1e-16f) + b1[lane];
    v = v > 0.f ? v : (__expf(v) - 1.f);   // ELU

    float p0 = v * W2[lane * 2 + 0];
    float p1 = v * W2[lane * 2 + 1];
#pragma unroll
    for (int o = 1; o < 64; o <<= 1) {
        p0 += __shfl_xor(p0, o, 64);
        p1 += __shfl_xor(p1, o, 64);
    }
    if (lane == 0) {
        float s2 = p0 * attS2[0] + p1 * attS2[1];
        float d2 = p0 * attD2[0] + p1 * attD2[1];
        node4[n] = make_float4(p0, p1, s2, d2);
    }
}

// -------- layer-2 gather + graph pool: one THREAD per node --------
__global__ __launch_bounds__(256) void k_gather2(const unsigned short* __restrict__ csr,
                                                 const int* __restrict__ row_start,
                                                 const float4* __restrict__ node4,
                                                 const int* __restrict__ batch,
                                                 const float* __restrict__ b2,
                                                 float* __restrict__ out) {
    __shared__ float pool[NSLOT][2];
    __shared__ int gbase_s;
    const int t = threadIdx.x;
    const int n = blockIdx.x * 256 + t;

    if (t == 0) gbase_s = batch[blockIdx.x * 256];
    for (int i = t; i < NSLOT * 2; i += 256) (&pool[0][0])[i] = 0.f;
    __syncthreads();

    if (n < NN) {
        const float4 vn = node4[n];
        const float aDd = vn.w;

        // self-loop
        float ev = vn.z + aDd;
        ev = fmaxf(ev, NEG * ev);
        float ex = __expf(ev);
        float den = ex, p0 = ex * vn.x, p1 = ex * vn.y;

        const int e0 = row_start[n], e1 = row_start[n + 1];
#pragma unroll 4
        for (int e = e0; e < e1; ++e) {
            int s = csr[e];
            float4 vs = node4[s];
            float ev2 = vs.z + aDd;
            ev2 = fmaxf(ev2, NEG * ev2);
            float ex2 = __expf(ev2);
            den += ex2;
            p0 = fmaf(ex2, vs.x, p0);
            p1 = fmaf(ex2, vs.y, p1);
        }
        float inv = 1.f / fmaxf(den, 1e-16f);
        float v0 = p0 * inv + b2[0];
        float v1 = p1 * inv + b2[1];

        int g = batch[n];
        int slot = g - gbase_s;
        if (slot < NSLOT) {
            atomicAdd(&pool[slot][0], v0);
            atomicAdd(&pool[slot][1], v1);
        } else {
            atomicAdd(&out[g * 2 + 0], v0);
            atomicAdd(&out[g * 2 + 1], v1);
        }
    }
    __syncthreads();
    for (int i = t; i < NSLOT; i += 256) {
        float v0 = pool[i][0], v1 = pool[i][1];
        if (v0 != 0.f || v1 != 0.f) {
            int g = gbase_s + i;
            atomicAdd(&out[g * 2 + 0], v0);
            atomicAdd(&out[g * 2 + 1], v1);
        }
    }
}

extern "C" void kernel_launch(void* const* d_in, const int* in_sizes, int n_in,
                              void* d_out, int out_size, void* d_ws, size_t ws_size,
                              hipStream_t stream) {
    const float* x     = (const float*)d_in[0];
    const int*   ei    = (const int*)d_in[1];
    const int*   batch = (const int*)d_in[2];
    const float* W1    = (const float*)d_in[3];
    const float* attS1 = (const float*)d_in[4];
    const float* attD1 = (const float*)d_in[5];
    const float* b1    = (const float*)d_in[6];
    const float* W2    = (const float*)d_in[7];
    const float* attS2 = (const float*)d_in[8];
    const float* attD2 = (const float*)d_in[9];
    const float* b2    = (const float*)d_in[10];
    float* out = (float*)d_out;

    int* ws = (int*)d_ws;
    __half* h1h = (__half*)ws;
    float* aS1 = (float*)(ws + (size_t)NN * 32);
    float* aD1 = (float*)(ws + (size_t)NN * 40);
    float4* node4 = (float4*)(ws + (size_t)NN * 48);
    int* row_start = ws + (size_t)NN * 52;
    int* bcount    = ws + (size_t)NN * 53 + 64;
    int* bbase     = ws + (size_t)NN * 53 + 464;
    int* bcursor   = ws + (size_t)NN * 53 + 864;
    unsigned* binned     = (unsigned*)(ws + (size_t)NN * 54);
    unsigned short* csr  = (unsigned short*)(ws + (size_t)NN * 54 + NE);

    k_zero<<<(NBKT + NG * 2 + 255) / 256, 256, 0, stream>>>(bcount, out);
    k_linear1<<<NN / 4, 256, 0, stream>>>(x, W1, attS1, attD1, h1h, aS1, aD1);
    k_bincount<<<256, 256, 0, stream>>>(ei, bcount);
    k_bucketscan<<<1, 512, 0, stream>>>(bcount, bbase, bcursor, row_start);
    k_binscatter<<<(NE + CHUNK - 1) / CHUNK, 256, 0, stream>>>(ei, bcursor, binned);
    k_buildcsr<<<NBKT, 256, 0, stream>>>(binned, bbase, row_start, csr);
    k_gather1<<<NN / 4, 256, 0, stream>>>(csr, row_start, aS1, aD1, h1h, b1, W2,
                                          attS2, attD2, node4);
    k_gather2<<<(NN + 255) / 256, 256, 0, stream>>>(csr, row_start, node4, batch, b2, out);
}

// Round 7
// 126.283 us; speedup vs baseline: 6.6034x; 1.2949x over previous
//
#include <hip/hip_runtime.h>
#include <hip/hip_fp16.h>

#define NN 50000
#define NE 1600000
#define NG 512
#define NEG 0.2f

#define NBKT 391            // ceil(50000/128) buckets of 128 dst nodes
#define CHUNK 4096          // edges per binscatter block
#define CAP 8192            // max edges per bucket (avg 4092, ~64 sigma margin)
#define NSLOT 32            // LDS graph-pool slots per block

typedef _Float16 half8 __attribute__((ext_vector_type(8)));
typedef float f32x4 __attribute__((ext_vector_type(4)));

// ---------------- workspace layout (4-byte words) ----------------
// h1h   [NN*64] half        @ 0
// aS1   [NN*8]  f           @ NN*32
// aD1   [NN*8]  f           @ NN*40
// node4 [NN*4]  f (h2_0,h2_1,aS2,aD2) @ NN*48
// row_start [NN+1] i        @ NN*52
// bucket_count [400] i      @ NN*53 + 64   <- zeroed each call
// bucket_base  [400] i      @ NN*53 + 464
// bucket_cursor[400] i      @ NN*53 + 864
// W1f   [20*64*8] f16 = 5120 w @ NN*53 + 2048
// binned [NE]  u32          @ NN*54
// csr    [NE]  u16          @ NN*54 + NE

__global__ __launch_bounds__(256) void k_zero(int* __restrict__ bcount,
                                              float* __restrict__ out) {
    int i = blockIdx.x * 256 + threadIdx.x;
    if (i < NBKT) bcount[i] = 0;
    else if (i < NBKT + NG * 2) out[i - NBKT] = 0.f;
}

// pack W1 (133x64 fp32) into MFMA B-fragments, f16, K padded to 160
__global__ __launch_bounds__(256) void k_prepw(const float* __restrict__ W1,
                                               _Float16* __restrict__ W1f) {
    int t = blockIdx.x * 256 + threadIdx.x;   // 1280 (frag, lane) pairs
    if (t >= 20 * 64) return;
    int f = t >> 6, l = t & 63;
    int kt = f >> 2, ct = f & 3;
    int g = l >> 4, c16 = l & 15;
#pragma unroll
    for (int i = 0; i < 8; ++i) {
        int k = kt * 32 + g * 8 + i;
        float v = (k < 133) ? W1[k * 64 + ct * 16 + c16] : 0.f;
        W1f[t * 8 + i] = (_Float16)v;
    }
}

// MFMA linear1: one wave per 16 nodes; h1 = x @ W1 + attention coefs
__global__ __launch_bounds__(256) void k_linmfma(const float* __restrict__ x,
                                                 const _Float16* __restrict__ W1f,
                                                 const float* __restrict__ attS,
                                                 const float* __restrict__ attD,
                                                 __half* __restrict__ h1h,
                                                 float* __restrict__ aS,
                                                 float* __restrict__ aD) {
    const int wid = (blockIdx.x * 256 + threadIdx.x) >> 6;
    const int nb  = wid * 16;
    if (nb >= NN) return;                 // NN % 16 == 0: full waves only
    const int l   = threadIdx.x & 63;
    const int g   = l >> 4, c16 = l & 15;
    const long xbase = (long)(nb + c16) * 133;   // A row for this lane

    // preload all B fragments (W1 entire, fragment-ordered)
    half8 bfr[5][4];
#pragma unroll
    for (int kt = 0; kt < 5; ++kt)
#pragma unroll
        for (int ct = 0; ct < 4; ++ct)
            bfr[kt][ct] = *reinterpret_cast<const half8*>(W1f + ((kt * 4 + ct) * 64 + l) * 8);

    f32x4 acc[4] = {{0.f,0.f,0.f,0.f},{0.f,0.f,0.f,0.f},{0.f,0.f,0.f,0.f},{0.f,0.f,0.f,0.f}};
#pragma unroll
    for (int kt = 0; kt < 5; ++kt) {
        half8 a;
#pragma unroll
        for (int i = 0; i < 8; ++i) {
            int k = kt * 32 + g * 8 + i;
            a[i] = (_Float16)((k < 133) ? x[xbase + k] : 0.f);
        }
#pragma unroll
        for (int ct = 0; ct < 4; ++ct)
            acc[ct] = __builtin_amdgcn_mfma_f32_16x16x32_f16(a, bfr[kt][ct], acc[ct], 0, 0, 0);
    }

    // epilogue: D[row=(l>>4)*4+r][col=ct*16+(l&15)]
#pragma unroll
    for (int ct = 0; ct < 4; ++ct) {
        const int col  = ct * 16 + c16;
        const int head = col >> 3;
        const float as_w = attS[head * 8 + (col & 7)];
        const float ad_w = attD[head * 8 + (col & 7)];
#pragma unroll
        for (int r = 0; r < 4; ++r) {
            const int n = nb + g * 4 + r;
            float v = acc[ct][r];
            h1h[n * 64 + col] = __float2half(v);
            float ps = v * as_w, pd = v * ad_w;
            ps += __shfl_xor(ps, 1, 64); pd += __shfl_xor(pd, 1, 64);
            ps += __shfl_xor(ps, 2, 64); pd += __shfl_xor(pd, 2, 64);
            ps += __shfl_xor(ps, 4, 64); pd += __shfl_xor(pd, 4, 64);
            if ((l & 7) == 0) {
                aS[n * 8 + head] = ps;
                aD[n * 8 + head] = pd;
            }
        }
    }
}

// -------- binned CSR build --------
__global__ __launch_bounds__(256) void k_bincount(const int* __restrict__ ei,
                                                  int* __restrict__ bcount) {
    __shared__ int hist[NBKT];
    for (int i = threadIdx.x; i < NBKT; i += 256) hist[i] = 0;
    __syncthreads();
    for (int e = blockIdx.x * 256 + threadIdx.x; e < NE; e += 256 * 256)
        atomicAdd(&hist[ei[NE + e] >> 7], 1);
    __syncthreads();
    for (int i = threadIdx.x; i < NBKT; i += 256) {
        int v = hist[i];
        if (v) atomicAdd(&bcount[i], v);
    }
}

__global__ __launch_bounds__(512) void k_bucketscan(const int* __restrict__ bcount,
                                                    int* __restrict__ bbase,
                                                    int* __restrict__ bcursor,
                                                    int* __restrict__ row_start) {
    __shared__ int s[512];
    const int t = threadIdx.x;
    int v = (t < NBKT) ? bcount[t] : 0;
    s[t] = v;
    __syncthreads();
    for (int o = 1; o < 512; o <<= 1) {
        int u = (t >= o) ? s[t - o] : 0;
        __syncthreads();
        s[t] += u;
        __syncthreads();
    }
    if (t < NBKT) {
        int ex = s[t] - v;   // exclusive
        bbase[t]   = ex;
        bcursor[t] = ex;
    }
    if (t == 0) {
        bbase[NBKT]   = NE;
        row_start[NN] = NE;
    }
}

__global__ __launch_bounds__(256) void k_binscatter(const int* __restrict__ ei,
                                                    int* __restrict__ bcursor,
                                                    unsigned* __restrict__ binned) {
    __shared__ int hist[NBKT];
    __shared__ int basel[NBKT];
    const int t = threadIdx.x;
    const int estart = blockIdx.x * CHUNK;

    for (int i = t; i < NBKT; i += 256) hist[i] = 0;
    __syncthreads();

    unsigned pk[16];
    int br[16];
#pragma unroll
    for (int i = 0; i < 16; ++i) {
        int e = estart + t + i * 256;
        if (e < NE) {
            int s = ei[e];
            int d = ei[NE + e];
            int b = d >> 7;
            int r = atomicAdd(&hist[b], 1);
            pk[i] = ((unsigned)s << 7) | (unsigned)(d & 127);
            br[i] = (r << 9) | b;         // r<4096 (13b), b<512 (9b)
        } else {
            br[i] = -1;
        }
    }
    __syncthreads();
    for (int i = t; i < NBKT; i += 256)
        basel[i] = hist[i] ? atomicAdd(&bcursor[i], hist[i]) : 0;
    __syncthreads();
#pragma unroll
    for (int i = 0; i < 16; ++i) {
        if (br[i] >= 0) {
            int b = br[i] & 511;
            int r = br[i] >> 9;
            binned[basel[b] + r] = pk[i];
        }
    }
}

__global__ __launch_bounds__(256) void k_buildcsr(const unsigned* __restrict__ binned,
                                                  const int* __restrict__ bbase,
                                                  int* __restrict__ row_start,
                                                  unsigned short* __restrict__ csr) {
    __shared__ unsigned edg[CAP];
    __shared__ unsigned short csrl[CAP];
    __shared__ int deg[128], scn[128], cur[128];

    const int b = blockIdx.x, t = threadIdx.x;
    const int ebase = bbase[b];
    const int ecnt  = min(bbase[b + 1] - ebase, CAP);
    const int nbase = b << 7;
    const int ncnt  = min(128, NN - nbase);

    for (int i = t; i < ecnt; i += 256) edg[i] = binned[ebase + i];
    if (t < 128) deg[t] = 0;
    __syncthreads();
    for (int i = t; i < ecnt; i += 256) atomicAdd(&deg[edg[i] & 127], 1);
    __syncthreads();
    if (t < 128) scn[t] = deg[t];
    __syncthreads();
    for (int o = 1; o < 128; o <<= 1) {
        int v = (t < 128 && t >= o) ? scn[t - o] : 0;
        __syncthreads();
        if (t < 128) scn[t] += v;
        __syncthreads();
    }
    if (t < 128) {
        int ex = scn[t] - deg[t];   // exclusive
        cur[t] = ex;
        if (t < ncnt) row_start[nbase + t] = ebase + ex;
    }
    __syncthreads();
    for (int i = t; i < ecnt; i += 256) {
        unsigned pk = edg[i];
        int pos = atomicAdd(&cur[pk & 127], 1);
        csrl[pos] = (unsigned short)(pk >> 7);
    }
    __syncthreads();
    for (int i = t; i < ecnt; i += 256) csr[ebase + i] = csrl[i];
}

// -------- layer-1 gather, two-phase; epilogue packs node4 --------
__global__ __launch_bounds__(256) void k_gather1(const unsigned short* __restrict__ csr,
                                                 const int* __restrict__ row_start,
                                                 const float* __restrict__ aS,
                                                 const float* __restrict__ aD,
                                                 const __half* __restrict__ h1h,
                                                 const float* __restrict__ b1,
                                                 const float* __restrict__ W2,
                                                 const float* __restrict__ attS2,
                                                 const float* __restrict__ attD2,
                                                 float4* __restrict__ node4) {
    __shared__ float exs[4][64 * 8];
    __shared__ int   svs[4][64];

    const int sub  = threadIdx.x >> 6;
    const int lane = threadIdx.x & 63;
    const int n    = (blockIdx.x * 256 + threadIdx.x) >> 6;  // grid exact
    const int h    = lane >> 3;   // head owned in phase 2 (col = lane)
    const int hp   = lane & 7;    // head owned in phase 1
    const int ebl  = lane >> 3;   // edge-within-pass in phase 1

    const float aDhp = aD[n * 8 + hp];
    const int e0 = row_start[n], e1 = row_start[n + 1];

    float acc = 0.f, den = 0.f;
    for (int base = e0; base < e1; base += 64) {
        const int cnt = min(64, e1 - base);
        int sv = (base + lane < e1) ? (int)csr[base + lane] : n;
        svs[sub][lane] = sv;

        // phase 1: edge-parallel exp weights
#pragma unroll
        for (int p = 0; p < 8; ++p) {
            int eb = p * 8 + ebl;
            int s  = svs[sub][eb];
            float ev = aS[s * 8 + hp] + aDhp;
            ev = fmaxf(ev, NEG * ev);            // leaky relu
            float ex = __expf(ev);
            if (eb >= cnt) ex = 0.f;             // zero-pad tail
            exs[sub][eb * 8 + hp] = ex;
        }

        // phase 2: column-parallel aggregation, unroll 8 (pads contribute 0)
        const int cnt8 = (cnt + 7) & ~7;
        for (int eb = 0; eb < cnt8; eb += 8) {
#pragma unroll
            for (int k = 0; k < 8; ++k) {
                int   s  = svs[sub][eb + k];
                float ex = exs[sub][(eb + k) * 8 + h];
                den += ex;
                acc = fmaf(ex, __half2float(h1h[s * 64 + lane]), acc);
            }
        }
    }
    // self-loop
    {
        float ev = aS[n * 8 + h] + aD[n * 8 + h];
        ev = fmaxf(ev, NEG * ev);
        float ex = __expf(ev);
        den += ex;
        acc = fmaf(ex, __half2float(h1h[n * 64 + lane]), acc);
    }
    float v = acc / fmaxf(den, 1e-16f) + b1[lane];
    v = v > 0.f ? v : (__expf(v) - 1.f);   // ELU

    float p0 = v * W2[lane * 2 + 0];
    float p1 = v * W2[lane * 2 + 1];
#pragma unroll
    for (int o = 1; o < 64; o <<= 1) {
        p0 += __shfl_xor(p0, o, 64);
        p1 += __shfl_xor(p1, o, 64);
    }
    if (lane == 0) {
        float s2 = p0 * attS2[0] + p1 * attS2[1];
        float d2 = p0 * attD2[0] + p1 * attD2[1];
        node4[n] = make_float4(p0, p1, s2, d2);
    }
}

// -------- layer-2 gather + graph pool: one THREAD per node --------
__global__ __launch_bounds__(256) void k_gather2(const unsigned short* __restrict__ csr,
                                                 const int* __restrict__ row_start,
                                                 const float4* __restrict__ node4,
                                                 const int* __restrict__ batch,
                                                 const float* __restrict__ b2,
                                                 float* __restrict__ out) {
    __shared__ float pool[NSLOT][2];
    __shared__ int gbase_s;
    const int t = threadIdx.x;
    const int n = blockIdx.x * 256 + t;

    if (t == 0) gbase_s = batch[blockIdx.x * 256];
    for (int i = t; i < NSLOT * 2; i += 256) (&pool[0][0])[i] = 0.f;
    __syncthreads();

    if (n < NN) {
        const float4 vn = node4[n];
        const float aDd = vn.w;

        // self-loop
        float ev = vn.z + aDd;
        ev = fmaxf(ev, NEG * ev);
        float ex = __expf(ev);
        float den = ex, p0 = ex * vn.x, p1 = ex * vn.y;

        const int e0 = row_start[n], e1 = row_start[n + 1];
#pragma unroll 4
        for (int e = e0; e < e1; ++e) {
            int s = csr[e];
            float4 vs = node4[s];
            float ev2 = vs.z + aDd;
            ev2 = fmaxf(ev2, NEG * ev2);
            float ex2 = __expf(ev2);
            den += ex2;
            p0 = fmaf(ex2, vs.x, p0);
            p1 = fmaf(ex2, vs.y, p1);
        }
        float inv = 1.f / fmaxf(den, 1e-16f);
        float v0 = p0 * inv + b2[0];
        float v1 = p1 * inv + b2[1];

        int g = batch[n];
        int slot = g - gbase_s;
        if (slot < NSLOT) {
            atomicAdd(&pool[slot][0], v0);
            atomicAdd(&pool[slot][1], v1);
        } else {
            atomicAdd(&out[g * 2 + 0], v0);
            atomicAdd(&out[g * 2 + 1], v1);
        }
    }
    __syncthreads();
    for (int i = t; i < NSLOT; i += 256) {
        float v0 = pool[i][0], v1 = pool[i][1];
        if (v0 != 0.f || v1 != 0.f) {
            int g = gbase_s + i;
            atomicAdd(&out[g * 2 + 0], v0);
            atomicAdd(&out[g * 2 + 1], v1);
        }
    }
}

extern "C" void kernel_launch(void* const* d_in, const int* in_sizes, int n_in,
                              void* d_out, int out_size, void* d_ws, size_t ws_size,
                              hipStream_t stream) {
    const float* x     = (const float*)d_in[0];
    const int*   ei    = (const int*)d_in[1];
    const int*   batch = (const int*)d_in[2];
    const float* W1    = (const float*)d_in[3];
    const float* attS1 = (const float*)d_in[4];
    const float* attD1 = (const float*)d_in[5];
    const float* b1    = (const float*)d_in[6];
    const float* W2    = (const float*)d_in[7];
    const float* attS2 = (const float*)d_in[8];
    const float* attD2 = (const float*)d_in[9];
    const float* b2    = (const float*)d_in[10];
    float* out = (float*)d_out;

    int* ws = (int*)d_ws;
    __half* h1h = (__half*)ws;
    float* aS1 = (float*)(ws + (size_t)NN * 32);
    float* aD1 = (float*)(ws + (size_t)NN * 40);
    float4* node4 = (float4*)(ws + (size_t)NN * 48);
    int* row_start = ws + (size_t)NN * 52;
    int* bcount    = ws + (size_t)NN * 53 + 64;
    int* bbase     = ws + (size_t)NN * 53 + 464;
    int* bcursor   = ws + (size_t)NN * 53 + 864;
    _Float16* W1f  = (_Float16*)(ws + (size_t)NN * 53 + 2048);
    unsigned* binned     = (unsigned*)(ws + (size_t)NN * 54);
    unsigned short* csr  = (unsigned short*)(ws + (size_t)NN * 54 + NE);

    k_zero<<<(NBKT + NG * 2 + 255) / 256, 256, 0, stream>>>(bcount, out);
    k_prepw<<<5, 256, 0, stream>>>(W1, W1f);
    k_linmfma<<<(NN / 16 + 3) / 4, 256, 0, stream>>>(x, W1f, attS1, attD1, h1h, aS1, aD1);
    k_bincount<<<256, 256, 0, stream>>>(ei, bcount);
    k_bucketscan<<<1, 512, 0, stream>>>(bcount, bbase, bcursor, row_start);
    k_binscatter<<<(NE + CHUNK - 1) / CHUNK, 256, 0, stream>>>(ei, bcursor, binned);
    k_buildcsr<<<NBKT, 256, 0, stream>>>(binned, bbase, row_start, csr);
    k_gather1<<<NN / 4, 256, 0, stream>>>(csr, row_start, aS1, aD1, h1h, b1, W2,
                                          attS2, attD2, node4);
    k_gather2<<<(NN + 255) / 256, 256, 0, stream>>>(csr, row_start, node4, batch, b2, out);
}

// Round 8
// 105.721 us; speedup vs baseline: 7.8877x; 1.1945x over previous
//
#include <hip/hip_runtime.h>
#include <hip/hip_fp16.h>

#define NN 50000
#define NE 1600000
#define NG 512
#define NEG 0.2f

#define NBKT 391            // ceil(50000/128) buckets of 128 dst nodes
#define CHUNK 4096          // edges per binscatter block
#define CAP 8192            // padded slot per bucket (mean 4096, sigma 64)
#define NSLOT 32            // LDS graph-pool slots per block

typedef _Float16 half8 __attribute__((ext_vector_type(8)));
typedef float f32x4 __attribute__((ext_vector_type(4)));

// ---------------- workspace layout (4-byte words) ----------------
// h1h/h1u [NN*64] half = NN*32 w @ 0
// aS1   [NN*8]  f           @ NN*32
// aD1   [NN*8]  f           @ NN*40
// node4 [NN*4]  f           @ NN*48
// row_se [NN] int2 = NN*2 w @ NN*52
// bcursor [391] i           @ NN*54      <- zeroed each call
// W1f   [1280*8] f16 = 2560w @ NN*54 + 512
// binned [NBKT*CAP] u32     @ NN*55
// csr    [NBKT*CAP] u16     @ NN*55 + NBKT*CAP
// total ~ 30.2 MB

// init: pack W1 fragments + zero bcursor + zero out
__global__ __launch_bounds__(256) void k_init(const float* __restrict__ W1,
                                              _Float16* __restrict__ W1f,
                                              int* __restrict__ bcursor,
                                              float* __restrict__ out) {
    int i = blockIdx.x * 256 + threadIdx.x;
    if (i < 1280) {
        int f = i >> 6, l = i & 63;
        int kt = f >> 2, ct = f & 3;
        int g = l >> 4, c16 = l & 15;
#pragma unroll
        for (int j = 0; j < 8; ++j) {
            int k = kt * 32 + g * 8 + j;
            float v = (k < 133) ? W1[k * 64 + ct * 16 + c16] : 0.f;
            W1f[i * 8 + j] = (_Float16)v;
        }
    } else if (i < 1280 + NBKT) {
        bcursor[i - 1280] = 0;
    } else if (i < 1280 + NBKT + NG * 2) {
        out[i - 1280 - NBKT] = 0.f;
    }
}

// MFMA linear1: one wave per 16 nodes; h1 = x @ W1 + attention coefs
__global__ __launch_bounds__(256) void k_linmfma(const float* __restrict__ x,
                                                 const _Float16* __restrict__ W1f,
                                                 const float* __restrict__ attS,
                                                 const float* __restrict__ attD,
                                                 __half* __restrict__ h1h,
                                                 float* __restrict__ aS,
                                                 float* __restrict__ aD) {
    const int wid = (blockIdx.x * 256 + threadIdx.x) >> 6;
    const int nb  = wid * 16;
    if (nb >= NN) return;
    const int l   = threadIdx.x & 63;
    const int g   = l >> 4, c16 = l & 15;
    const long xbase = (long)(nb + c16) * 133;

    half8 bfr[5][4];
#pragma unroll
    for (int kt = 0; kt < 5; ++kt)
#pragma unroll
        for (int ct = 0; ct < 4; ++ct)
            bfr[kt][ct] = *reinterpret_cast<const half8*>(W1f + ((kt * 4 + ct) * 64 + l) * 8);

    f32x4 acc[4] = {{0.f,0.f,0.f,0.f},{0.f,0.f,0.f,0.f},{0.f,0.f,0.f,0.f},{0.f,0.f,0.f,0.f}};
#pragma unroll
    for (int kt = 0; kt < 5; ++kt) {
        half8 a;
#pragma unroll
        for (int i = 0; i < 8; ++i) {
            int k = kt * 32 + g * 8 + i;
            a[i] = (_Float16)((k < 133) ? x[xbase + k] : 0.f);
        }
#pragma unroll
        for (int ct = 0; ct < 4; ++ct)
            acc[ct] = __builtin_amdgcn_mfma_f32_16x16x32_f16(a, bfr[kt][ct], acc[ct], 0, 0, 0);
    }

#pragma unroll
    for (int ct = 0; ct < 4; ++ct) {
        const int col  = ct * 16 + c16;
        const int head = col >> 3;
        const float as_w = attS[head * 8 + (col & 7)];
        const float ad_w = attD[head * 8 + (col & 7)];
#pragma unroll
        for (int r = 0; r < 4; ++r) {
            const int n = nb + g * 4 + r;
            float v = acc[ct][r];
            h1h[n * 64 + col] = __float2half(v);
            float ps = v * as_w, pd = v * ad_w;
            ps += __shfl_xor(ps, 1, 64); pd += __shfl_xor(pd, 1, 64);
            ps += __shfl_xor(ps, 2, 64); pd += __shfl_xor(pd, 2, 64);
            ps += __shfl_xor(ps, 4, 64); pd += __shfl_xor(pd, 4, 64);
            if ((l & 7) == 0) {
                aS[n * 8 + head] = ps;
                aD[n * 8 + head] = pd;
            }
        }
    }
}

// binscatter into padded buckets (no pre-count needed)
__global__ __launch_bounds__(256) void k_binscatter(const int* __restrict__ ei,
                                                    int* __restrict__ bcursor,
                                                    unsigned* __restrict__ binned) {
    __shared__ int hist[NBKT];
    __shared__ int basel[NBKT];
    const int t = threadIdx.x;
    const int estart = blockIdx.x * CHUNK;

    for (int i = t; i < NBKT; i += 256) hist[i] = 0;
    __syncthreads();

    unsigned pk[16];
    int br[16];
#pragma unroll
    for (int i = 0; i < 16; ++i) {
        int e = estart + t + i * 256;
        if (e < NE) {
            int s = ei[e];
            int d = ei[NE + e];
            int b = d >> 7;
            int r = atomicAdd(&hist[b], 1);
            pk[i] = ((unsigned)s << 7) | (unsigned)(d & 127);
            br[i] = (r << 9) | b;            // r < 4096 fits
        } else {
            br[i] = -1;
        }
    }
    __syncthreads();
    for (int i = t; i < NBKT; i += 256)
        basel[i] = hist[i] ? (i * CAP + atomicAdd(&bcursor[i], hist[i])) : 0;
    __syncthreads();
#pragma unroll
    for (int i = 0; i < 16; ++i) {
        if (br[i] >= 0) {
            int b = br[i] & 511;
            int r = br[i] >> 9;
            int pos = basel[b] + r;
            if (pos < (b + 1) * CAP) binned[pos] = pk[i];
        }
    }
}

__global__ __launch_bounds__(256) void k_buildcsr(const unsigned* __restrict__ binned,
                                                  const int* __restrict__ bcursor,
                                                  int2* __restrict__ row_se,
                                                  unsigned short* __restrict__ csr) {
    __shared__ unsigned edg[CAP];
    __shared__ unsigned short csrl[CAP];
    __shared__ int deg[128], scn[128], cur[128];

    const int b = blockIdx.x, t = threadIdx.x;
    const int ebase = b * CAP;
    const int ecnt  = min(bcursor[b], CAP);
    const int nbase = b << 7;
    const int ncnt  = min(128, NN - nbase);

    for (int i = t; i < ecnt; i += 256) edg[i] = binned[ebase + i];
    if (t < 128) deg[t] = 0;
    __syncthreads();
    for (int i = t; i < ecnt; i += 256) atomicAdd(&deg[edg[i] & 127], 1);
    __syncthreads();
    if (t < 128) scn[t] = deg[t];
    __syncthreads();
    for (int o = 1; o < 128; o <<= 1) {
        int v = (t < 128 && t >= o) ? scn[t - o] : 0;
        __syncthreads();
        if (t < 128) scn[t] += v;
        __syncthreads();
    }
    if (t < 128) {
        cur[t] = scn[t] - deg[t];
        if (t < ncnt) row_se[nbase + t] = make_int2(ebase + scn[t] - deg[t], ebase + scn[t]);
    }
    __syncthreads();
    for (int i = t; i < ecnt; i += 256) {
        unsigned pk = edg[i];
        int pos = atomicAdd(&cur[pk & 127], 1);
        csrl[pos] = (unsigned short)(pk >> 7);
    }
    __syncthreads();
    for (int i = t; i < ecnt; i += 256) csr[ebase + i] = csrl[i];
}

// -------- layer-1 gather: 2 edges per iteration, half2 loads --------
__global__ __launch_bounds__(256) void k_gather1(const unsigned short* __restrict__ csr,
                                                 const int2* __restrict__ row_se,
                                                 const float* __restrict__ aS,
                                                 const float* __restrict__ aD,
                                                 const unsigned* __restrict__ h1u,
                                                 const float* __restrict__ b1,
                                                 const float* __restrict__ W2,
                                                 const float* __restrict__ attS2,
                                                 const float* __restrict__ attD2,
                                                 float4* __restrict__ node4) {
    __shared__ float exs[4][64 * 8];
    __shared__ int   svs[4][64];

    const int sub  = threadIdx.x >> 6;
    const int lane = threadIdx.x & 63;
    const int n    = (blockIdx.x * 256 + threadIdx.x) >> 6;  // grid exact
    const int hp   = lane & 7;    // phase-1 head
    const int ebl  = lane >> 3;   // phase-1 edge slot
    const int half = lane >> 5;   // phase-2 edge parity
    const int c    = lane & 31;   // phase-2 col pair (2c, 2c+1)
    const int hc   = c >> 2;      // head of those cols

    const float aDhp = aD[n * 8 + hp];
    const int2 se = row_se[n];
    const int e0 = se.x, e1 = se.y;

    float2 acc = make_float2(0.f, 0.f);
    float den = 0.f;   // per-lane partial for head hp
    for (int base = e0; base < e1; base += 64) {
        const int cnt = min(64, e1 - base);
        int sv = (base + lane < e1) ? (int)csr[base + lane] : n;
        svs[sub][lane] = sv;

        // phase 1: edge-parallel exp weights (+ den partial)
#pragma unroll
        for (int p = 0; p < 8; ++p) {
            int eb = p * 8 + ebl;
            int s  = svs[sub][eb];
            float ev = aS[s * 8 + hp] + aDhp;
            ev = fmaxf(ev, NEG * ev);
            float ex = __expf(ev);
            if (eb >= cnt) ex = 0.f;
            exs[sub][eb * 8 + hp] = ex;
            den += ex;
        }

        // phase 2: 2 edges per step, half2 columns
        const int cnt8 = (cnt + 7) & ~7;
        for (int eb = 0; eb < cnt8; eb += 8) {
#pragma unroll
            for (int k = 0; k < 8; k += 2) {
                int   e2 = eb + k + half;
                int   s  = svs[sub][e2];
                float ex = exs[sub][e2 * 8 + hc];
                unsigned hv = h1u[s * 32 + c];
                float2 f2 = __half22float2(*reinterpret_cast<__half2*>(&hv));
                acc.x = fmaf(ex, f2.x, acc.x);
                acc.y = fmaf(ex, f2.y, acc.y);
            }
        }
    }
    // reduce den across edge-slot groups (lanes sharing hp)
    den += __shfl_xor(den, 8, 64);
    den += __shfl_xor(den, 16, 64);
    den += __shfl_xor(den, 32, 64);
    // self-loop (per-head)
    float ev_s = aS[n * 8 + hp] + aDhp;
    ev_s = fmaxf(ev_s, NEG * ev_s);
    float ex_self = __expf(ev_s);
    den += ex_self;

    // fold the two edge-halves
    acc.x += __shfl_xor(acc.x, 32, 64);
    acc.y += __shfl_xor(acc.y, 32, 64);

    // broadcast per-head values to column lanes
    float den_c = __shfl(den, hc, 64);
    float ex_sc = __shfl(ex_self, hc, 64);

    // lanes 0-31 finish cols 2c, 2c+1
    unsigned hvs = h1u[n * 32 + c];
    float2 fs = __half22float2(*reinterpret_cast<__half2*>(&hvs));
    float inv = 1.f / fmaxf(den_c, 1e-16f);
    float2 bb = reinterpret_cast<const float2*>(b1)[c];
    float vx = fmaf(ex_sc, fs.x, acc.x) * inv + bb.x;
    float vy = fmaf(ex_sc, fs.y, acc.y) * inv + bb.y;
    vx = vx > 0.f ? vx : (__expf(vx) - 1.f);
    vy = vy > 0.f ? vy : (__expf(vy) - 1.f);

    float4 w = reinterpret_cast<const float4*>(W2)[c];  // (W2[2c][0],W2[2c][1],W2[2c+1][0],W2[2c+1][1])
    float p0 = vx * w.x + vy * w.z;
    float p1 = vx * w.y + vy * w.w;
    // reduce over lanes 0-31 (xor <=16 stays within half)
    p0 += __shfl_xor(p0, 1, 64);  p1 += __shfl_xor(p1, 1, 64);
    p0 += __shfl_xor(p0, 2, 64);  p1 += __shfl_xor(p1, 2, 64);
    p0 += __shfl_xor(p0, 4, 64);  p1 += __shfl_xor(p1, 4, 64);
    p0 += __shfl_xor(p0, 8, 64);  p1 += __shfl_xor(p1, 8, 64);
    p0 += __shfl_xor(p0, 16, 64); p1 += __shfl_xor(p1, 16, 64);
    if (lane == 0) {
        float s2 = p0 * attS2[0] + p1 * attS2[1];
        float d2 = p0 * attD2[0] + p1 * attD2[1];
        node4[n] = make_float4(p0, p1, s2, d2);
    }
}

// -------- layer-2 gather + graph pool: one THREAD per node --------
__global__ __launch_bounds__(256) void k_gather2(const unsigned short* __restrict__ csr,
                                                 const int2* __restrict__ row_se,
                                                 const float4* __restrict__ node4,
                                                 const int* __restrict__ batch,
                                                 const float* __restrict__ b2,
                                                 float* __restrict__ out) {
    __shared__ float pool[NSLOT][2];
    __shared__ int gbase_s;
    const int t = threadIdx.x;
    const int n = blockIdx.x * 256 + t;

    if (t == 0) gbase_s = batch[blockIdx.x * 256];
    for (int i = t; i < NSLOT * 2; i += 256) (&pool[0][0])[i] = 0.f;
    __syncthreads();

    if (n < NN) {
        const float4 vn = node4[n];
        const float aDd = vn.w;

        float ev = vn.z + aDd;
        ev = fmaxf(ev, NEG * ev);
        float ex = __expf(ev);
        float den = ex, p0 = ex * vn.x, p1 = ex * vn.y;

        const int2 se = row_se[n];
#pragma unroll 4
        for (int e = se.x; e < se.y; ++e) {
            int s = csr[e];
            float4 vs = node4[s];
            float ev2 = vs.z + aDd;
            ev2 = fmaxf(ev2, NEG * ev2);
            float ex2 = __expf(ev2);
            den += ex2;
            p0 = fmaf(ex2, vs.x, p0);
            p1 = fmaf(ex2, vs.y, p1);
        }
        float inv = 1.f / fmaxf(den, 1e-16f);
        float v0 = p0 * inv + b2[0];
        float v1 = p1 * inv + b2[1];

        int g = batch[n];
        int slot = g - gbase_s;
        if (slot < NSLOT) {
            atomicAdd(&pool[slot][0], v0);
            atomicAdd(&pool[slot][1], v1);
        } else {
            atomicAdd(&out[g * 2 + 0], v0);
            atomicAdd(&out[g * 2 + 1], v1);
        }
    }
    __syncthreads();
    for (int i = t; i < NSLOT; i += 256) {
        float v0 = pool[i][0], v1 = pool[i][1];
        if (v0 != 0.f || v1 != 0.f) {
            int g = gbase_s + i;
            atomicAdd(&out[g * 2 + 0], v0);
            atomicAdd(&out[g * 2 + 1], v1);
        }
    }
}

extern "C" void kernel_launch(void* const* d_in, const int* in_sizes, int n_in,
                              void* d_out, int out_size, void* d_ws, size_t ws_size,
                              hipStream_t stream) {
    const float* x     = (const float*)d_in[0];
    const int*   ei    = (const int*)d_in[1];
    const int*   batch = (const int*)d_in[2];
    const float* W1    = (const float*)d_in[3];
    const float* attS1 = (const float*)d_in[4];
    const float* attD1 = (const float*)d_in[5];
    const float* b1    = (const float*)d_in[6];
    const float* W2    = (const float*)d_in[7];
    const float* attS2 = (const float*)d_in[8];
    const float* attD2 = (const float*)d_in[9];
    const float* b2    = (const float*)d_in[10];
    float* out = (float*)d_out;

    int* ws = (int*)d_ws;
    __half* h1h = (__half*)ws;
    unsigned* h1u = (unsigned*)ws;
    float* aS1 = (float*)(ws + (size_t)NN * 32);
    float* aD1 = (float*)(ws + (size_t)NN * 40);
    float4* node4 = (float4*)(ws + (size_t)NN * 48);
    int2* row_se  = (int2*)(ws + (size_t)NN * 52);
    int* bcursor  = ws + (size_t)NN * 54;
    _Float16* W1f = (_Float16*)(ws + (size_t)NN * 54 + 512);
    unsigned* binned    = (unsigned*)(ws + (size_t)NN * 55);
    unsigned short* csr = (unsigned short*)(ws + (size_t)NN * 55 + (size_t)NBKT * CAP);

    k_init<<<(1280 + NBKT + NG * 2 + 255) / 256, 256, 0, stream>>>(W1, W1f, bcursor, out);
    k_linmfma<<<(NN / 16 + 3) / 4, 256, 0, stream>>>(x, W1f, attS1, attD1, h1h, aS1, aD1);
    k_binscatter<<<(NE + CHUNK - 1) / CHUNK, 256, 0, stream>>>(ei, bcursor, binned);
    k_buildcsr<<<NBKT, 256, 0, stream>>>(binned, bcursor, row_se, csr);
    k_gather1<<<NN / 4, 256, 0, stream>>>(csr, row_se, aS1, aD1, h1u, b1, W2,
                                          attS2, attD2, node4);
    k_gather2<<<(NN + 255) / 256, 256, 0, stream>>>(csr, row_se, node4, batch, b2, out);
}

// Round 9
// 100.031 us; speedup vs baseline: 8.3364x; 1.0569x over previous
//
#include <hip/hip_runtime.h>
#include <hip/hip_fp16.h>

#define NN 50000
#define NE 1600000
#define NG 512
#define NEG 0.2f

#define NBKT 782            // ceil(50000/64) buckets of 64 dst nodes
#define CHUNK 8192          // edges per binscatter block
#define NSB ((NE + CHUNK - 1) / CHUNK)   // 196 binscatter blocks
#define CAP 3072            // padded slots per bucket (mean 2048, sigma 45)
#define NBL 782             // linmfma blocks: ceil(NN/16/4)
#define NSLOT 32            // LDS graph-pool slots per block

typedef _Float16 half8 __attribute__((ext_vector_type(8)));
typedef float f32x4 __attribute__((ext_vector_type(4)));

// ---------------- workspace layout (4-byte words) ----------------
// h1h/h1u [NN*64] half = NN*32 w @ 0
// aS1   [NN*8]  f           @ NN*32
// aD1   [NN*8]  f           @ NN*40
// node4 [NN*4]  f           @ NN*48
// row_se [NN] int2 = NN*2 w @ NN*52
// bcursor [782*16] i        @ NN*54      <- line-padded (1 counter / 64B), zeroed each call
// W1f   [1280*8] f16 = 2560w @ NN*54 + 12544
// binned [NBKT*CAP] u32     @ NN*55
// csr    [NBKT*CAP] u16     @ NN*55 + NBKT*CAP
// total ~ 25.4 MB

// init: pack W1 fragments + zero bcursor + zero out
__global__ __launch_bounds__(256) void k_init(const float* __restrict__ W1,
                                              _Float16* __restrict__ W1f,
                                              int* __restrict__ bcursor,
                                              float* __restrict__ out) {
    int i = blockIdx.x * 256 + threadIdx.x;
    if (i < 1280) {
        int f = i >> 6, l = i & 63;
        int kt = f >> 2, ct = f & 3;
        int g = l >> 4, c16 = l & 15;
#pragma unroll
        for (int j = 0; j < 8; ++j) {
            int k = kt * 32 + g * 8 + j;
            float v = (k < 133) ? W1[k * 64 + ct * 16 + c16] : 0.f;
            W1f[i * 8 + j] = (_Float16)v;
        }
    } else if (i < 1280 + NBKT * 16) {
        bcursor[i - 1280] = 0;
    } else if (i < 1280 + NBKT * 16 + NG * 2) {
        out[i - 1280 - NBKT * 16] = 0.f;
    }
}

// union kernel: blocks [0,NBL) = MFMA linear1; blocks [NBL,NBL+NSB) = binscatter
__global__ __launch_bounds__(256) void k_mfma_scatter(const float* __restrict__ x,
                                                      const _Float16* __restrict__ W1f,
                                                      const float* __restrict__ attS,
                                                      const float* __restrict__ attD,
                                                      __half* __restrict__ h1h,
                                                      float* __restrict__ aS,
                                                      float* __restrict__ aD,
                                                      const int* __restrict__ ei,
                                                      int* __restrict__ bcursor,
                                                      unsigned* __restrict__ binned) {
    if (blockIdx.x < NBL) {
        // ---- MFMA linear1: one wave per 16 nodes ----
        const int wid = (blockIdx.x * 256 + threadIdx.x) >> 6;
        const int nb  = wid * 16;
        if (nb >= NN) return;
        const int l   = threadIdx.x & 63;
        const int g   = l >> 4, c16 = l & 15;
        const long xbase = (long)(nb + c16) * 133;

        half8 bfr[5][4];
#pragma unroll
        for (int kt = 0; kt < 5; ++kt)
#pragma unroll
            for (int ct = 0; ct < 4; ++ct)
                bfr[kt][ct] = *reinterpret_cast<const half8*>(W1f + ((kt * 4 + ct) * 64 + l) * 8);

        f32x4 acc[4] = {{0.f,0.f,0.f,0.f},{0.f,0.f,0.f,0.f},{0.f,0.f,0.f,0.f},{0.f,0.f,0.f,0.f}};
#pragma unroll
        for (int kt = 0; kt < 5; ++kt) {
            half8 a;
#pragma unroll
            for (int i = 0; i < 8; ++i) {
                int k = kt * 32 + g * 8 + i;
                a[i] = (_Float16)((k < 133) ? x[xbase + k] : 0.f);
            }
#pragma unroll
            for (int ct = 0; ct < 4; ++ct)
                acc[ct] = __builtin_amdgcn_mfma_f32_16x16x32_f16(a, bfr[kt][ct], acc[ct], 0, 0, 0);
        }

#pragma unroll
        for (int ct = 0; ct < 4; ++ct) {
            const int col  = ct * 16 + c16;
            const int head = col >> 3;
            const float as_w = attS[head * 8 + (col & 7)];
            const float ad_w = attD[head * 8 + (col & 7)];
#pragma unroll
            for (int r = 0; r < 4; ++r) {
                const int n = nb + g * 4 + r;
                float v = acc[ct][r];
                h1h[n * 64 + col] = __float2half(v);
                float ps = v * as_w, pd = v * ad_w;
                ps += __shfl_xor(ps, 1, 64); pd += __shfl_xor(pd, 1, 64);
                ps += __shfl_xor(ps, 2, 64); pd += __shfl_xor(pd, 2, 64);
                ps += __shfl_xor(ps, 4, 64); pd += __shfl_xor(pd, 4, 64);
                if ((l & 7) == 0) {
                    aS[n * 8 + head] = ps;
                    aD[n * 8 + head] = pd;
                }
            }
        }
    } else {
        // ---- binscatter into padded buckets ----
        __shared__ int hist[NBKT];
        __shared__ int basel[NBKT];
        const int t = threadIdx.x;
        const int estart = (blockIdx.x - NBL) * CHUNK;

        for (int i = t; i < NBKT; i += 256) hist[i] = 0;
        __syncthreads();

        unsigned pk[32];
        int br[32];
#pragma unroll
        for (int i = 0; i < 32; ++i) {
            int e = estart + t + i * 256;
            if (e < NE) {
                int s = ei[e];
                int d = ei[NE + e];
                int b = d >> 6;
                int r = atomicAdd(&hist[b], 1);
                pk[i] = ((unsigned)s << 6) | (unsigned)(d & 63);
                br[i] = (r << 10) | b;          // r<8192 (13b), b<1024 (10b)
            } else {
                br[i] = -1;
            }
        }
        __syncthreads();
        for (int i = t; i < NBKT; i += 256)
            basel[i] = hist[i] ? (i * CAP + atomicAdd(&bcursor[i * 16], hist[i])) : 0;
        __syncthreads();
#pragma unroll
        for (int i = 0; i < 32; ++i) {
            if (br[i] >= 0) {
                int b = br[i] & 1023;
                int r = br[i] >> 10;
                int pos = basel[b] + r;
                if (pos < (b + 1) * CAP) binned[pos] = pk[i];
            }
        }
    }
}

// per-bucket LDS counting sort -> csr + row_se
__global__ __launch_bounds__(256) void k_buildcsr(const unsigned* __restrict__ binned,
                                                  const int* __restrict__ bcursor,
                                                  int2* __restrict__ row_se,
                                                  unsigned short* __restrict__ csr) {
    __shared__ unsigned edg[CAP];
    __shared__ unsigned short csrl[CAP];
    __shared__ int deg[64], scn[64], cur[64];

    const int b = blockIdx.x, t = threadIdx.x;
    const int ebase = b * CAP;
    const int ecnt  = min(bcursor[b * 16], CAP);
    const int nbase = b << 6;
    const int ncnt  = min(64, NN - nbase);

    for (int i = t; i < ecnt; i += 256) edg[i] = binned[ebase + i];
    if (t < 64) deg[t] = 0;
    __syncthreads();
    for (int i = t; i < ecnt; i += 256) atomicAdd(&deg[edg[i] & 63], 1);
    __syncthreads();
    if (t < 64) scn[t] = deg[t];
    __syncthreads();
    for (int o = 1; o < 64; o <<= 1) {
        int v = (t < 64 && t >= o) ? scn[t - o] : 0;
        __syncthreads();
        if (t < 64) scn[t] += v;
        __syncthreads();
    }
    if (t < 64) {
        cur[t] = scn[t] - deg[t];
        if (t < ncnt) row_se[nbase + t] = make_int2(ebase + scn[t] - deg[t], ebase + scn[t]);
    }
    __syncthreads();
    for (int i = t; i < ecnt; i += 256) {
        unsigned pk = edg[i];
        int pos = atomicAdd(&cur[pk & 63], 1);
        csrl[pos] = (unsigned short)(pk >> 6);
    }
    __syncthreads();
    for (int i = t; i < ecnt; i += 256) csr[ebase + i] = csrl[i];
}

// -------- layer-1 gather: 2 edges per iteration, half2 loads --------
__global__ __launch_bounds__(256) void k_gather1(const unsigned short* __restrict__ csr,
                                                 const int2* __restrict__ row_se,
                                                 const float* __restrict__ aS,
                                                 const float* __restrict__ aD,
                                                 const unsigned* __restrict__ h1u,
                                                 const float* __restrict__ b1,
                                                 const float* __restrict__ W2,
                                                 const float* __restrict__ attS2,
                                                 const float* __restrict__ attD2,
                                                 float4* __restrict__ node4) {
    __shared__ float exs[4][64 * 8];
    __shared__ int   svs[4][64];

    const int sub  = threadIdx.x >> 6;
    const int lane = threadIdx.x & 63;
    const int n    = (blockIdx.x * 256 + threadIdx.x) >> 6;  // grid exact
    const int hp   = lane & 7;    // phase-1 head
    const int ebl  = lane >> 3;   // phase-1 edge slot
    const int half = lane >> 5;   // phase-2 edge parity
    const int c    = lane & 31;   // phase-2 col pair (2c, 2c+1)
    const int hc   = c >> 2;      // head of those cols

    const float aDhp = aD[n * 8 + hp];
    const int2 se = row_se[n];
    const int e0 = se.x, e1 = se.y;

    float2 acc = make_float2(0.f, 0.f);
    float den = 0.f;   // per-lane partial for head hp
    for (int base = e0; base < e1; base += 64) {
        const int cnt = min(64, e1 - base);
        int sv = (base + lane < e1) ? (int)csr[base + lane] : n;
        svs[sub][lane] = sv;

        // phase 1: edge-parallel exp weights (+ den partial)
#pragma unroll
        for (int p = 0; p < 8; ++p) {
            int eb = p * 8 + ebl;
            int s  = svs[sub][eb];
            float ev = aS[s * 8 + hp] + aDhp;
            ev = fmaxf(ev, NEG * ev);
            float ex = __expf(ev);
            if (eb >= cnt) ex = 0.f;
            exs[sub][eb * 8 + hp] = ex;
            den += ex;
        }

        // phase 2: 2 edges per step, half2 columns
        const int cnt8 = (cnt + 7) & ~7;
        for (int eb = 0; eb < cnt8; eb += 8) {
#pragma unroll
            for (int k = 0; k < 8; k += 2) {
                int   e2 = eb + k + half;
                int   s  = svs[sub][e2];
                float ex = exs[sub][e2 * 8 + hc];
                unsigned hv = h1u[s * 32 + c];
                float2 f2 = __half22float2(*reinterpret_cast<__half2*>(&hv));
                acc.x = fmaf(ex, f2.x, acc.x);
                acc.y = fmaf(ex, f2.y, acc.y);
            }
        }
    }
    // reduce den across edge-slot groups (lanes sharing hp)
    den += __shfl_xor(den, 8, 64);
    den += __shfl_xor(den, 16, 64);
    den += __shfl_xor(den, 32, 64);
    // self-loop (per-head)
    float ev_s = aS[n * 8 + hp] + aDhp;
    ev_s = fmaxf(ev_s, NEG * ev_s);
    float ex_self = __expf(ev_s);
    den += ex_self;

    // fold the two edge-halves
    acc.x += __shfl_xor(acc.x, 32, 64);
    acc.y += __shfl_xor(acc.y, 32, 64);

    // broadcast per-head values to column lanes
    float den_c = __shfl(den, hc, 64);
    float ex_sc = __shfl(ex_self, hc, 64);

    // lanes 0-31 finish cols 2c, 2c+1
    unsigned hvs = h1u[n * 32 + c];
    float2 fs = __half22float2(*reinterpret_cast<__half2*>(&hvs));
    float inv = 1.f / fmaxf(den_c, 1e-16f);
    float2 bb = reinterpret_cast<const float2*>(b1)[c];
    float vx = fmaf(ex_sc, fs.x, acc.x) * inv + bb.x;
    float vy = fmaf(ex_sc, fs.y, acc.y) * inv + bb.y;
    vx = vx > 0.f ? vx : (__expf(vx) - 1.f);
    vy = vy > 0.f ? vy : (__expf(vy) - 1.f);

    float4 w = reinterpret_cast<const float4*>(W2)[c];
    float p0 = vx * w.x + vy * w.z;
    float p1 = vx * w.y + vy * w.w;
    p0 += __shfl_xor(p0, 1, 64);  p1 += __shfl_xor(p1, 1, 64);
    p0 += __shfl_xor(p0, 2, 64);  p1 += __shfl_xor(p1, 2, 64);
    p0 += __shfl_xor(p0, 4, 64);  p1 += __shfl_xor(p1, 4, 64);
    p0 += __shfl_xor(p0, 8, 64);  p1 += __shfl_xor(p1, 8, 64);
    p0 += __shfl_xor(p0, 16, 64); p1 += __shfl_xor(p1, 16, 64);
    if (lane == 0) {
        float s2 = p0 * attS2[0] + p1 * attS2[1];
        float d2 = p0 * attD2[0] + p1 * attD2[1];
        node4[n] = make_float4(p0, p1, s2, d2);
    }
}

// -------- layer-2 gather + graph pool: one THREAD per node --------
__global__ __launch_bounds__(256) void k_gather2(const unsigned short* __restrict__ csr,
                                                 const int2* __restrict__ row_se,
                                                 const float4* __restrict__ node4,
                                                 const int* __restrict__ batch,
                                                 const float* __restrict__ b2,
                                                 float* __restrict__ out) {
    __shared__ float pool[NSLOT][2];
    __shared__ int gbase_s;
    const int t = threadIdx.x;
    const int n = blockIdx.x * 256 + t;

    if (t == 0) gbase_s = batch[blockIdx.x * 256];
    for (int i = t; i < NSLOT * 2; i += 256) (&pool[0][0])[i] = 0.f;
    __syncthreads();

    if (n < NN) {
        const float4 vn = node4[n];
        const float aDd = vn.w;

        float ev = vn.z + aDd;
        ev = fmaxf(ev, NEG * ev);
        float ex = __expf(ev);
        float den = ex, p0 = ex * vn.x, p1 = ex * vn.y;

        const int2 se = row_se[n];
#pragma unroll 4
        for (int e = se.x; e < se.y; ++e) {
            int s = csr[e];
            float4 vs = node4[s];
            float ev2 = vs.z + aDd;
            ev2 = fmaxf(ev2, NEG * ev2);
            float ex2 = __expf(ev2);
            den += ex2;
            p0 = fmaf(ex2, vs.x, p0);
            p1 = fmaf(ex2, vs.y, p1);
        }
        float inv = 1.f / fmaxf(den, 1e-16f);
        float v0 = p0 * inv + b2[0];
        float v1 = p1 * inv + b2[1];

        int g = batch[n];
        int slot = g - gbase_s;
        if (slot < NSLOT) {
            atomicAdd(&pool[slot][0], v0);
            atomicAdd(&pool[slot][1], v1);
        } else {
            atomicAdd(&out[g * 2 + 0], v0);
            atomicAdd(&out[g * 2 + 1], v1);
        }
    }
    __syncthreads();
    for (int i = t; i < NSLOT; i += 256) {
        float v0 = pool[i][0], v1 = pool[i][1];
        if (v0 != 0.f || v1 != 0.f) {
            int g = gbase_s + i;
            atomicAdd(&out[g * 2 + 0], v0);
            atomicAdd(&out[g * 2 + 1], v1);
        }
    }
}

extern "C" void kernel_launch(void* const* d_in, const int* in_sizes, int n_in,
                              void* d_out, int out_size, void* d_ws, size_t ws_size,
                              hipStream_t stream) {
    const float* x     = (const float*)d_in[0];
    const int*   ei    = (const int*)d_in[1];
    const int*   batch = (const int*)d_in[2];
    const float* W1    = (const float*)d_in[3];
    const float* attS1 = (const float*)d_in[4];
    const float* attD1 = (const float*)d_in[5];
    const float* b1    = (const float*)d_in[6];
    const float* W2    = (const float*)d_in[7];
    const float* attS2 = (const float*)d_in[8];
    const float* attD2 = (const float*)d_in[9];
    const float* b2    = (const float*)d_in[10];
    float* out = (float*)d_out;

    int* ws = (int*)d_ws;
    __half* h1h = (__half*)ws;
    unsigned* h1u = (unsigned*)ws;
    float* aS1 = (float*)(ws + (size_t)NN * 32);
    float* aD1 = (float*)(ws + (size_t)NN * 40);
    float4* node4 = (float4*)(ws + (size_t)NN * 48);
    int2* row_se  = (int2*)(ws + (size_t)NN * 52);
    int* bcursor  = ws + (size_t)NN * 54;
    _Float16* W1f = (_Float16*)(ws + (size_t)NN * 54 + 12544);
    unsigned* binned    = (unsigned*)(ws + (size_t)NN * 55);
    unsigned short* csr = (unsigned short*)(ws + (size_t)NN * 55 + (size_t)NBKT * CAP);

    k_init<<<(1280 + NBKT * 16 + NG * 2 + 255) / 256, 256, 0, stream>>>(W1, W1f, bcursor, out);
    k_mfma_scatter<<<NBL + NSB, 256, 0, stream>>>(x, W1f, attS1, attD1, h1h, aS1, aD1,
                                                  ei, bcursor, binned);
    k_buildcsr<<<NBKT, 256, 0, stream>>>(binned, bcursor, row_se, csr);
    k_gather1<<<NN / 4, 256, 0, stream>>>(csr, row_se, aS1, aD1, h1u, b1, W2,
                                          attS2, attD2, node4);
    k_gather2<<<(NN + 255) / 256, 256, 0, stream>>>(csr, row_se, node4, batch, b2, out);
}